// Round 6
// baseline (276.124 us; speedup 1.0000x reference)
//
#include <hip/hip_runtime.h>
#include <hip/hip_bf16.h>
#include <stdint.h>

// MHA fwd: x[4,2048,1024] fp32, w_qkv[3072,1024], w_o[1024,1024]
// bf16 MFMA pipeline: cast -> QKV gemm (scale folded into q; V stored
// tile-major, 16B-unit XOR swizzle) -> flash attention -> out gemm.
// R11: flash PV/rowsum on full-rate K=32 mfma_16x16x32_bf16 via permuted
// QK key->row map (two packexp halves concatenate in-register).
// R12: flash LDS reads hoisted away from consumers (ds_read latency was the
// critical path after R11 cut MFMA-pipe time exactly as predicted).
// R13: v_cvt_pk_bf16_f32 attempt -> FAILED first check at 3.69e-2: its
// operand->half packing is not src0->low on this toolchain (pair-swapped P
// predicts exactly 0.02-0.04 error; measured 0.037).
// R14: RNE via known-bit-exact ops: f2bf-style round adjust on each exp2
// result, THEN the verified perm 0x07060302 hi16 pack. Unbiased (cures R12's
// post-timing margin failure) with zero semantic uncertainty. Keeps R13's
// sched_barrier(0) insurance + T1 XCD swizzle on both GEMMs (exonerated by
// error-magnitude analysis).

#define B_   4
#define T_   2048
#define H_   16
#define DK_  64
#define C_   1024
#define M_   (B_*T_)    // 8192 rows
#define N1_  (3*C_)     // 3072
#define LOG2E 1.44269504088896340736f
#define SCFOLD (0.125f * LOG2E)   // folded into q at QKV epilogue

using short8  = __attribute__((ext_vector_type(8))) short;
using short4v = __attribute__((ext_vector_type(4))) short;
using f32x4   = __attribute__((ext_vector_type(4))) float;
typedef unsigned short u16;

__device__ __forceinline__ u16 f2bf(float f) {       // RNE (used in epilogues)
  unsigned u = __float_as_uint(f);
  u += 0x7FFF + ((u >> 16) & 1);
  return (u16)(u >> 16);
}

// exp2 + RNE-to-bf16 + pack 4 floats -> short4v: 4 exp + 4 rne-adjust + 2 perm.
// RNE adjust (u += 0x7FFF + lsb(hi16)) before the hi16 byte-perm extraction --
// bit-exact same rounding as f2bf, packing via the R3-verified perm trick.
// NaN-safe: exp2 outputs are positive normals.
__device__ __forceinline__ short4v packexp(f32x4 s) {
  unsigned u0 = __float_as_uint(__builtin_amdgcn_exp2f(s[0]));
  unsigned u1 = __float_as_uint(__builtin_amdgcn_exp2f(s[1]));
  unsigned u2 = __float_as_uint(__builtin_amdgcn_exp2f(s[2]));
  unsigned u3 = __float_as_uint(__builtin_amdgcn_exp2f(s[3]));
  u0 += 0x7FFF + ((u0 >> 16) & 1);
  u1 += 0x7FFF + ((u1 >> 16) & 1);
  u2 += 0x7FFF + ((u2 >> 16) & 1);
  u3 += 0x7FFF + ((u3 >> 16) & 1);
  union { unsigned w[2]; short4v s4; } cv;
  cv.w[0] = __builtin_amdgcn_perm(u1, u0, 0x07060302);  // {hi16(u1),hi16(u0)}
  cv.w[1] = __builtin_amdgcn_perm(u3, u2, 0x07060302);  // {hi16(u3),hi16(u2)}
  return cv.s4;
}

__device__ __forceinline__ short8 cat44(short4v a, short4v b) {
  return __builtin_shufflevector(a, b, 0, 1, 2, 3, 4, 5, 6, 7);
}

// async global->LDS, 16B per lane; lds ptr is wave-uniform base, HW adds lane*16
__device__ __forceinline__ void gld_lds16(void* lds, const void* g) {
  __builtin_amdgcn_global_load_lds(
      (__attribute__((address_space(1))) void*)(g),
      (__attribute__((address_space(3))) void*)(lds), 16, 0, 0);
}

// ---------------- fp32 -> bf16 cast (all three tensors, one launch) ----------
__global__ void cast_all(const float* __restrict__ x, const float* __restrict__ wq,
                         const float* __restrict__ wo, u16* __restrict__ xb,
                         u16* __restrict__ wqb, u16* __restrict__ wob) {
  const int nx = M_ * C_ / 4, nq = N1_ * C_ / 4;
  int i = blockIdx.x * blockDim.x + threadIdx.x;
  const float* src; u16* dst; int j;
  if (i < nx)            { src = x;  dst = xb;  j = i; }
  else if (i < nx + nq)  { src = wq; dst = wqb; j = i - nx; }
  else                   { src = wo; dst = wob; j = i - nx - nq; }
  float4 v = ((const float4*)src)[j];
  ushort4 o;
  o.x = f2bf(v.x); o.y = f2bf(v.y); o.z = f2bf(v.z); o.w = f2bf(v.w);
  ((ushort4*)dst)[j] = o;
}

// ---------------- BT GEMM: C[m,n] = sum_k A[m,k]*B[n,k] ----------------
// 128x128 tile, BK=32, 4 waves in 2x2, each wave 64x64 (4x4 MFMA 16x16x32).
// R13: T1 XCD-aware block swizzle (bijective, nwg%8==0 for both launches):
// each XCD sweeps a contiguous chunk of tiles -> A-panels + B stay L2-local.
// MODE 0: epilogue scatters qkv -> q[B,H,T,64] (pre-scaled by SCFOLD),
//         k[B,H,T,64], and V in flash-ready tile-major swizzled layout.
// MODE 1: epilogue writes fp32 C row-major [M,N]
template <int MODE>
__global__ __launch_bounds__(256)
void gemm_bt(const u16* __restrict__ A, const u16* __restrict__ Bm,
             void* __restrict__ out0, void* __restrict__ out1, void* __restrict__ out2,
             int K, int N) {
  __shared__ __attribute__((aligned(16))) u16 As[128 * 32];
  __shared__ __attribute__((aligned(16))) u16 Bs[128 * 32];
  const int tid  = threadIdx.x;
  const int w    = tid >> 6, lane = tid & 63;
  const int quad = lane >> 4, l15 = lane & 15;
  const int wm   = w >> 1, wn = w & 1;

  // XCD swizzle: launch order round-robins XCDs; remap so XCD i owns tiles
  // [i*cpx, (i+1)*cpx) in n-fastest order (T1; valid since nwg % 8 == 0).
  const int nxb = gridDim.x, nwg = nxb * gridDim.y;
  int flat = blockIdx.y * nxb + blockIdx.x;
  if ((nwg & 7) == 0) flat = (flat & 7) * (nwg >> 3) + (flat >> 3);
  const int m0 = (flat / nxb) * 128, n0 = (flat % nxb) * 128;

  f32x4 acc[4][4];
#pragma unroll
  for (int i = 0; i < 4; i++)
#pragma unroll
    for (int j = 0; j < 4; j++) acc[i][j] = f32x4{0.f, 0.f, 0.f, 0.f};

  const int nkt = K >> 5;
  for (int kt = 0; kt < nkt; ++kt) {
    __syncthreads();
    // stage A,B tiles: 128x32 bf16 = 8KB each = 512 chunks of 16B
#pragma unroll
    for (int c = 0; c < 2; ++c) {
      int chunk = c * 256 + tid;
      int row = chunk >> 2, col = (chunk & 3) << 3;
      gld_lds16(As + (c * 256 + w * 64) * 8, A  + (size_t)(m0 + row) * K + kt * 32 + col);
      gld_lds16(Bs + (c * 256 + w * 64) * 8, Bm + (size_t)(n0 + row) * K + kt * 32 + col);
    }
    __syncthreads();
    short8 af[4], bf[4];
#pragma unroll
    for (int i = 0; i < 4; i++)
      af[i] = *(const short8*)(As + (wm * 64 + i * 16 + l15) * 32 + quad * 8);
#pragma unroll
    for (int j = 0; j < 4; j++)
      bf[j] = *(const short8*)(Bs + (wn * 64 + j * 16 + l15) * 32 + quad * 8);
#pragma unroll
    for (int i = 0; i < 4; i++)
#pragma unroll
      for (int j = 0; j < 4; j++)
        acc[i][j] = __builtin_amdgcn_mfma_f32_16x16x32_bf16(af[i], bf[j], acc[i][j], 0, 0, 0);
  }

  // epilogue: C/D layout col=lane&15, row=quad*4+reg  (m89-verified)
  if (MODE == 0) {
    u16* q  = (u16*)out0;
    u16* k  = (u16*)out1;
    u16* vt = (u16*)out2;
#pragma unroll
    for (int i = 0; i < 4; i++) {
      int m = m0 + wm * 64 + i * 16 + quad * 4;   // + r below, never crosses b boundary
      int b = m >> 11, t = m & 2047;              // t multiple of 4
#pragma unroll
      for (int j = 0; j < 4; j++) {
        int f = n0 + wn * 64 + j * 16 + l15;
        int s = f >> 10, h = (f >> 6) & 15, d = f & 63;
        if (s == 2) {
          ushort4 pk;                              // keys t..t+3 of dim d
          pk.x = f2bf(acc[i][j][0]); pk.y = f2bf(acc[i][j][1]);
          pk.z = f2bf(acc[i][j][2]); pk.w = f2bf(acc[i][j][3]);
          int kt2  = t >> 6;
          int cw   = (t >> 3) & 7;                 // 8-key (16B) unit
          int pw   = cw ^ (d & 7);                 // bank-free b128 flash reads
          int half = (t >> 2) & 1;
          *(ushort4*)(vt + ((((size_t)(b * H_ + h) * 32 + kt2) * 64 + d) * 8 + pw) * 8 + half * 4) = pk;
        } else {
          u16* dst = (s == 0) ? q : k;
          float sc = (s == 0) ? SCFOLD : 1.0f;
#pragma unroll
          for (int r = 0; r < 4; r++)
            dst[(((size_t)(b * H_ + h)) * T_ + (t + r)) * DK_ + d] = f2bf(acc[i][j][r] * sc);
        }
      }
    }
  } else {
    float* outp = (float*)out0;
#pragma unroll
    for (int i = 0; i < 4; i++) {
      int m = m0 + wm * 64 + i * 16 + quad * 4;
#pragma unroll
      for (int j = 0; j < 4; j++) {
        int n = n0 + wn * 64 + j * 16 + l15;
#pragma unroll
        for (int r = 0; r < 4; r++)
          outp[(size_t)(m + r) * N + n] = acc[i][j][r];
      }
    }
  }
}

// ---------------- flash attention (K=32 PV, hoisted LDS reads) --------------
// grid (B*H, T/128), 256 thr. Wave w owns 32 Q-rows (2 x 16).
// S^T = K·Q^T via 16x16x32 with PERMUTED key->MFMA-row map: unit (u,h) loads
// K rows 32u + 8*(l15>>2) + 4h + (l15&3), so output reg r at lane (quad,l15)
// holds key 32u + 8*quad + 4h + r.  packexp(alpha)++packexp(beta) is then
// EXACTLY the K=32 A-fragment (k = quad*8 + j, keys 32u+8*quad..+7): PV and
// rowsum run as mfma_f32_16x16x32_bf16 (full-rate) with zero cross-lane ops.
// R12 schedule: all 8 K-frag reads + V(0) reads burst at tile top, then
// QK(0) -> QK(1) -> exp(0) -> read V(1) -> PV(0) -> exp(1) -> PV(1).
// Every ds_read is >=~150cy of issue distance from its consumer.
// R13: sched_barrier(0) after __syncthreads() pins the burst below the
// barrier (anti-hoist insurance). R14: packexp is RNE via bit-exact ops.
__global__ __launch_bounds__(256)
void flash_kernel(const u16* __restrict__ Q, const u16* __restrict__ Kg,
                  const u16* __restrict__ Vt, u16* __restrict__ AO) {
  __shared__ __attribute__((aligned(16))) u16 KVs[2][2][64 * 64];  // [buf][K/V]
  const int tid  = threadIdx.x;
  const int w    = tid >> 6, lane = tid & 63;
  const int quad = lane >> 4, l15 = lane & 15;
  const int bh   = blockIdx.x;
  const int q0   = blockIdx.y * 128;
  const u16* Qb = Q  + (size_t)bh * T_ * DK_;
  const u16* Kb = Kg + (size_t)bh * T_ * DK_;
  const u16* Vb = Vt + (size_t)bh * T_ * DK_;   // 32 tiles x 4096 u16, contiguous

  // Q fragments (B-operand of S^T = K·Q^T): lane n=q=l15 holds d=quad*8+j.
  short8 qf[2][2];
#pragma unroll
  for (int mi = 0; mi < 2; mi++)
#pragma unroll
    for (int ks = 0; ks < 2; ks++)
      qf[mi][ks] = *(const short8*)(Qb + (size_t)(q0 + w * 32 + mi * 16 + l15) * DK_ + ks * 32 + quad * 8);

  // ones A/B-fragment (bf16 1.0 x8) for K=32 rowsum MFMA
  short8 ones8;
#pragma unroll
  for (int z = 0; z < 8; z++) ones8[z] = (short)0x3F80;

  f32x4 O[2][4];       // rows q=quad*4+r, cols d=dj*16+l15 (C/D layout)
  f32x4 rowsum[2];
#pragma unroll
  for (int mi = 0; mi < 2; mi++) {
    rowsum[mi] = f32x4{0.f, 0.f, 0.f, 0.f};
#pragma unroll
    for (int dj = 0; dj < 4; dj++) O[mi][dj] = f32x4{0.f, 0.f, 0.f, 0.f};
  }

  const int swz = l15 & 7;
  const int NT  = T_ / 64;
  // kt-invariant LDS offsets (elements)
  const int koff0 = ((quad) ^ swz) * 8;            // d 0..31 K chunk
  const int koff1 = ((4 + quad) ^ swz) * 8;        // d 32..63 K chunk
  const int rA    = ((l15 >> 2) << 3) + (l15 & 3); // permuted key-row base
  const int voffu0 = ((quad) ^ swz) * 8;           // u=0 V chunk
  const int voffu1 = ((4 + quad) ^ swz) * 8;       // u=1 V chunk

  // stage tile kt into buffer b (async DMA). K: source-swizzled 16B chunks
  // with f(row) = (row&3)|(((row>>3)&1)<<2). V: linear copy (pre-swizzled).
  auto stage = [&](int kt, int b) {
#pragma unroll
    for (int c = 0; c < 2; ++c) {
      int s = c * 256 + tid;
      int row = s >> 3;
      int cc  = (s & 7) ^ ((row & 3) | (((row >> 3) & 1) << 2));
      gld_lds16(&KVs[b][0][(c * 256 + w * 64) * 8], Kb + (size_t)kt * 4096 + row * 64 + cc * 8);
      gld_lds16(&KVs[b][1][(c * 256 + w * 64) * 8], Vb + (size_t)kt * 4096 + s * 8);
    }
  };

  stage(0, 0);   // prologue

  for (int kt = 0; kt < NT; ++kt) {
    __syncthreads();               // DMA for buf[kt&1] landed during last iter
    __builtin_amdgcn_sched_barrier(0);   // pin: nothing below moves above
    if (kt + 1 < NT) stage(kt + 1, (kt + 1) & 1);   // hidden by compute below
    const u16* Ks = KVs[kt & 1][0];
    const u16* Vs = KVs[kt & 1][1];

    // ---- read burst: all K fragments (both units) + V fragments for u=0 ----
    const u16* krA0 = Ks + (rA)          * 64;   // u=0 h=0: keys 8*quad + r
    const u16* krB0 = Ks + (rA + 4)      * 64;   // u=0 h=1: keys 8*quad+4+r
    const u16* krA1 = Ks + (32 + rA)     * 64;   // u=1 h=0
    const u16* krB1 = Ks + (32 + rA + 4) * 64;   // u=1 h=1
    short8 ka0_0 = *(const short8*)(krA0 + koff0);
    short8 ka1_0 = *(const short8*)(krA0 + koff1);
    short8 kb0_0 = *(const short8*)(krB0 + koff0);
    short8 kb1_0 = *(const short8*)(krB0 + koff1);
    short8 ka0_1 = *(const short8*)(krA1 + koff0);
    short8 ka1_1 = *(const short8*)(krA1 + koff1);
    short8 kb0_1 = *(const short8*)(krB1 + koff0);
    short8 kb1_1 = *(const short8*)(krB1 + koff1);
    short8 vf0[4];
#pragma unroll
    for (int dj = 0; dj < 4; dj++)
      vf0[dj] = *(const short8*)(Vs + (dj * 16 + l15) * 64 + voffu0);

    // ---- QK(0): 8 MFMA ----
    f32x4 sA0c = f32x4{0.f, 0.f, 0.f, 0.f}, sA1c = sA0c, sB0c = sA0c, sB1c = sA0c;
    sA0c = __builtin_amdgcn_mfma_f32_16x16x32_bf16(ka0_0, qf[0][0], sA0c, 0, 0, 0);
    sA0c = __builtin_amdgcn_mfma_f32_16x16x32_bf16(ka1_0, qf[0][1], sA0c, 0, 0, 0);
    sA1c = __builtin_amdgcn_mfma_f32_16x16x32_bf16(ka0_0, qf[1][0], sA1c, 0, 0, 0);
    sA1c = __builtin_amdgcn_mfma_f32_16x16x32_bf16(ka1_0, qf[1][1], sA1c, 0, 0, 0);
    sB0c = __builtin_amdgcn_mfma_f32_16x16x32_bf16(kb0_0, qf[0][0], sB0c, 0, 0, 0);
    sB0c = __builtin_amdgcn_mfma_f32_16x16x32_bf16(kb1_0, qf[0][1], sB0c, 0, 0, 0);
    sB1c = __builtin_amdgcn_mfma_f32_16x16x32_bf16(kb0_0, qf[1][0], sB1c, 0, 0, 0);
    sB1c = __builtin_amdgcn_mfma_f32_16x16x32_bf16(kb1_0, qf[1][1], sB1c, 0, 0, 0);

    // ---- QK(1): 8 MFMA (K-frags read ~12 reads + 8 MFMAs ago) ----
    f32x4 sA0n = f32x4{0.f, 0.f, 0.f, 0.f}, sA1n = sA0n, sB0n = sA0n, sB1n = sA0n;
    sA0n = __builtin_amdgcn_mfma_f32_16x16x32_bf16(ka0_1, qf[0][0], sA0n, 0, 0, 0);
    sA0n = __builtin_amdgcn_mfma_f32_16x16x32_bf16(ka1_1, qf[0][1], sA0n, 0, 0, 0);
    sA1n = __builtin_amdgcn_mfma_f32_16x16x32_bf16(ka0_1, qf[1][0], sA1n, 0, 0, 0);
    sA1n = __builtin_amdgcn_mfma_f32_16x16x32_bf16(ka1_1, qf[1][1], sA1n, 0, 0, 0);
    sB0n = __builtin_amdgcn_mfma_f32_16x16x32_bf16(kb0_1, qf[0][0], sB0n, 0, 0, 0);
    sB0n = __builtin_amdgcn_mfma_f32_16x16x32_bf16(kb1_1, qf[0][1], sB0n, 0, 0, 0);
    sB1n = __builtin_amdgcn_mfma_f32_16x16x32_bf16(kb0_1, qf[1][0], sB1n, 0, 0, 0);
    sB1n = __builtin_amdgcn_mfma_f32_16x16x32_bf16(kb1_1, qf[1][1], sB1n, 0, 0, 0);

    // ---- exp/pack(0) (QK(0) results are 16 MFMAs old) ----
    short8 pa0 = cat44(packexp(sA0c), packexp(sB0c));
    short8 pa1 = cat44(packexp(sA1c), packexp(sB1c));

    // ---- read V fragments for u=1 (consumed after PV(0)+exp(1)) ----
    short8 vf1[4];
#pragma unroll
    for (int dj = 0; dj < 4; dj++)
      vf1[dj] = *(const short8*)(Vs + (dj * 16 + l15) * 64 + voffu1);

    // ---- rowsum(0) + PV(0): 10 MFMA (vf0 read at tile top) ----
    rowsum[0] = __builtin_amdgcn_mfma_f32_16x16x32_bf16(pa0, ones8, rowsum[0], 0, 0, 0);
    rowsum[1] = __builtin_amdgcn_mfma_f32_16x16x32_bf16(pa1, ones8, rowsum[1], 0, 0, 0);
#pragma unroll
    for (int dj = 0; dj < 4; dj++) {
      O[0][dj] = __builtin_amdgcn_mfma_f32_16x16x32_bf16(pa0, vf0[dj], O[0][dj], 0, 0, 0);
      O[1][dj] = __builtin_amdgcn_mfma_f32_16x16x32_bf16(pa1, vf0[dj], O[1][dj], 0, 0, 0);
    }

    // ---- exp/pack(1) ----
    short8 pb0 = cat44(packexp(sA0n), packexp(sB0n));
    short8 pb1 = cat44(packexp(sA1n), packexp(sB1n));

    // ---- rowsum(1) + PV(1): 10 MFMA (vf1 covered by PV(0)+exp(1)) ----
    rowsum[0] = __builtin_amdgcn_mfma_f32_16x16x32_bf16(pb0, ones8, rowsum[0], 0, 0, 0);
    rowsum[1] = __builtin_amdgcn_mfma_f32_16x16x32_bf16(pb1, ones8, rowsum[1], 0, 0, 0);
#pragma unroll
    for (int dj = 0; dj < 4; dj++) {
      O[0][dj] = __builtin_amdgcn_mfma_f32_16x16x32_bf16(pb0, vf1[dj], O[0][dj], 0, 0, 0);
      O[1][dj] = __builtin_amdgcn_mfma_f32_16x16x32_bf16(pb1, vf1[dj], O[1][dj], 0, 0, 0);
    }
  }

  // epilogue: rowsum[mi][r] holds the full key-sum for q-row quad*4+r
  const int b = bh >> 4, h = bh & 15;
#pragma unroll
  for (int mi = 0; mi < 2; mi++) {
#pragma unroll
    for (int r = 0; r < 4; r++) {
      float inv = 1.0f / rowsum[mi][r];
      int t = q0 + w * 32 + mi * 16 + quad * 4 + r;
#pragma unroll
      for (int dj = 0; dj < 4; dj++)
        AO[((size_t)(b * T_ + t)) * C_ + h * DK_ + dj * 16 + l15] = f2bf(O[mi][dj][r] * inv);
    }
  }
}

extern "C" void kernel_launch(void* const* d_in, const int* in_sizes, int n_in,
                              void* d_out, int out_size, void* d_ws, size_t ws_size,
                              hipStream_t stream) {
  const float* x    = (const float*)d_in[0];
  const float* wqkv = (const float*)d_in[1];
  const float* wo   = (const float*)d_in[2];

  char* p = (char*)d_ws;
  u16* xb    = (u16*)p; p += (size_t)M_ * C_ * 2;     // 16.8 MB
  u16* wqkvb = (u16*)p; p += (size_t)N1_ * C_ * 2;    //  6.3 MB
  u16* wob   = (u16*)p; p += (size_t)C_ * C_ * 2;     //  2.1 MB
  u16* qb    = (u16*)p; p += (size_t)M_ * C_ * 2;     // 16.8 MB  [B,H,T,64]
  u16* kb    = (u16*)p; p += (size_t)M_ * C_ * 2;     // 16.8 MB  [B,H,T,64]
  u16* vtb   = (u16*)p; p += (size_t)M_ * C_ * 2;     // 16.8 MB  tile-major swizzled
  u16* aob   = (u16*)p; p += (size_t)M_ * C_ * 2;     // 16.8 MB  [B,T,C]

  const int ncast = (M_ * C_ + N1_ * C_ + C_ * C_) / 4;
  cast_all<<<(ncast + 255) / 256, 256, 0, stream>>>(x, wqkv, wo, xb, wqkvb, wob);

  gemm_bt<0><<<dim3(N1_ / 128, M_ / 128), 256, 0, stream>>>(xb, wqkvb, qb, kb, vtb, C_, N1_);

  // grid (bh, qb): flat%8 == bh%8 -> all q-blocks of a head on one XCD
  flash_kernel<<<dim3(B_ * H_, T_ / 128), 256, 0, stream>>>(qb, kb, vtb, aob);

  gemm_bt<1><<<dim3(C_ / 128, M_ / 128), 256, 0, stream>>>(aob, wob, d_out, nullptr, nullptr, C_, C_);
}

// Round 8
// 271.350 us; speedup vs baseline: 1.0176x; 1.0176x over previous
//
#include <hip/hip_runtime.h>
#include <hip/hip_bf16.h>
#include <stdint.h>

// MHA fwd: x[4,2048,1024] fp32, w_qkv[3072,1024], w_o[1024,1024]
// bf16 MFMA pipeline: cast -> QKV gemm (scale folded into q; V stored
// tile-major, 16B-unit XOR swizzle) -> flash attention -> out gemm.
// R11: flash PV/rowsum on full-rate K=32 mfma_16x16x32_bf16 via permuted
// QK key->row map (two packexp halves concatenate in-register).
// R12: flash LDS reads hoisted away from consumers (ds_read latency was the
// critical path; R4 timing confirmed flash ~84.6us).
// R13/R14 post-mortem: R6 flash regressed to 105us. sched_barrier(0) is a
// FULL fence (blocks reg-only MFMA sinking across the barrier -> kills
// loop-carried overlap) and the 3-op RNE adjust put ~96 VALU/kt on the
// exp->pack->MFMA dep chain. Race theory dead on mechanism review (compiler
// drains vmcnt+lgkmcnt before s_barrier; single-barrier dbuf is correct).
// R15: drop sched_barrier(0); rounding = half-up (u += 0x8000, 1 op, literal
// in v_add src0) -- kills truncation's systematic bias (R12's post-timing
// failure) at measure-zero tie bias. GEMMs keep T1 XCD swizzle (~9us win).

#define B_   4
#define T_   2048
#define H_   16
#define DK_  64
#define C_   1024
#define M_   (B_*T_)    // 8192 rows
#define N1_  (3*C_)     // 3072
#define LOG2E 1.44269504088896340736f
#define SCFOLD (0.125f * LOG2E)   // folded into q at QKV epilogue

using short8  = __attribute__((ext_vector_type(8))) short;
using short4v = __attribute__((ext_vector_type(4))) short;
using f32x4   = __attribute__((ext_vector_type(4))) float;
typedef unsigned short u16;

__device__ __forceinline__ u16 f2bf(float f) {       // RNE (used in epilogues)
  unsigned u = __float_as_uint(f);
  u += 0x7FFF + ((u >> 16) & 1);
  return (u16)(u >> 16);
}

// exp2 + round-half-up-to-bf16 + pack 4 floats -> short4v: 4 exp + 4 add +
// 2 perm. u += 0x8000 before hi16 extraction = round-to-nearest (ties up):
// unbiased in practice (ties measure-zero for exp2 outputs), 1 VALU op/value
// (literal legal in v_add_u32 src0). Cures R12's truncation-bias post-timing
// failure without R14's 3-op RNE chain. NaN-safe: exp2 outputs are positive
// normals; +0x8000 cannot carry into NaN/inf for values < 2^127.
__device__ __forceinline__ short4v packexp(f32x4 s) {
  unsigned u0 = __float_as_uint(__builtin_amdgcn_exp2f(s[0])) + 0x8000u;
  unsigned u1 = __float_as_uint(__builtin_amdgcn_exp2f(s[1])) + 0x8000u;
  unsigned u2 = __float_as_uint(__builtin_amdgcn_exp2f(s[2])) + 0x8000u;
  unsigned u3 = __float_as_uint(__builtin_amdgcn_exp2f(s[3])) + 0x8000u;
  union { unsigned w[2]; short4v s4; } cv;
  cv.w[0] = __builtin_amdgcn_perm(u1, u0, 0x07060302);  // {hi16(u1),hi16(u0)}
  cv.w[1] = __builtin_amdgcn_perm(u3, u2, 0x07060302);  // {hi16(u3),hi16(u2)}
  return cv.s4;
}

__device__ __forceinline__ short8 cat44(short4v a, short4v b) {
  return __builtin_shufflevector(a, b, 0, 1, 2, 3, 4, 5, 6, 7);
}

// async global->LDS, 16B per lane; lds ptr is wave-uniform base, HW adds lane*16
__device__ __forceinline__ void gld_lds16(void* lds, const void* g) {
  __builtin_amdgcn_global_load_lds(
      (__attribute__((address_space(1))) void*)(g),
      (__attribute__((address_space(3))) void*)(lds), 16, 0, 0);
}

// ---------------- fp32 -> bf16 cast (all three tensors, one launch) ----------
__global__ void cast_all(const float* __restrict__ x, const float* __restrict__ wq,
                         const float* __restrict__ wo, u16* __restrict__ xb,
                         u16* __restrict__ wqb, u16* __restrict__ wob) {
  const int nx = M_ * C_ / 4, nq = N1_ * C_ / 4;
  int i = blockIdx.x * blockDim.x + threadIdx.x;
  const float* src; u16* dst; int j;
  if (i < nx)            { src = x;  dst = xb;  j = i; }
  else if (i < nx + nq)  { src = wq; dst = wqb; j = i - nx; }
  else                   { src = wo; dst = wob; j = i - nx - nq; }
  float4 v = ((const float4*)src)[j];
  ushort4 o;
  o.x = f2bf(v.x); o.y = f2bf(v.y); o.z = f2bf(v.z); o.w = f2bf(v.w);
  ((ushort4*)dst)[j] = o;
}

// ---------------- BT GEMM: C[m,n] = sum_k A[m,k]*B[n,k] ----------------
// 128x128 tile, BK=32, 4 waves in 2x2, each wave 64x64 (4x4 MFMA 16x16x32).
// T1 XCD-aware block swizzle (bijective, nwg%8==0 for both launches):
// each XCD sweeps a contiguous chunk of tiles -> A-panels + B stay L2-local.
// MODE 0: epilogue scatters qkv -> q[B,H,T,64] (pre-scaled by SCFOLD),
//         k[B,H,T,64], and V in flash-ready tile-major swizzled layout.
// MODE 1: epilogue writes fp32 C row-major [M,N]
template <int MODE>
__global__ __launch_bounds__(256)
void gemm_bt(const u16* __restrict__ A, const u16* __restrict__ Bm,
             void* __restrict__ out0, void* __restrict__ out1, void* __restrict__ out2,
             int K, int N) {
  __shared__ __attribute__((aligned(16))) u16 As[128 * 32];
  __shared__ __attribute__((aligned(16))) u16 Bs[128 * 32];
  const int tid  = threadIdx.x;
  const int w    = tid >> 6, lane = tid & 63;
  const int quad = lane >> 4, l15 = lane & 15;
  const int wm   = w >> 1, wn = w & 1;

  // XCD swizzle: launch order round-robins XCDs; remap so XCD i owns tiles
  // [i*cpx, (i+1)*cpx) in n-fastest order (T1; valid since nwg % 8 == 0).
  const int nxb = gridDim.x, nwg = nxb * gridDim.y;
  int flat = blockIdx.y * nxb + blockIdx.x;
  if ((nwg & 7) == 0) flat = (flat & 7) * (nwg >> 3) + (flat >> 3);
  const int m0 = (flat / nxb) * 128, n0 = (flat % nxb) * 128;

  f32x4 acc[4][4];
#pragma unroll
  for (int i = 0; i < 4; i++)
#pragma unroll
    for (int j = 0; j < 4; j++) acc[i][j] = f32x4{0.f, 0.f, 0.f, 0.f};

  const int nkt = K >> 5;
  for (int kt = 0; kt < nkt; ++kt) {
    __syncthreads();
    // stage A,B tiles: 128x32 bf16 = 8KB each = 512 chunks of 16B
#pragma unroll
    for (int c = 0; c < 2; ++c) {
      int chunk = c * 256 + tid;
      int row = chunk >> 2, col = (chunk & 3) << 3;
      gld_lds16(As + (c * 256 + w * 64) * 8, A  + (size_t)(m0 + row) * K + kt * 32 + col);
      gld_lds16(Bs + (c * 256 + w * 64) * 8, Bm + (size_t)(n0 + row) * K + kt * 32 + col);
    }
    __syncthreads();
    short8 af[4], bf[4];
#pragma unroll
    for (int i = 0; i < 4; i++)
      af[i] = *(const short8*)(As + (wm * 64 + i * 16 + l15) * 32 + quad * 8);
#pragma unroll
    for (int j = 0; j < 4; j++)
      bf[j] = *(const short8*)(Bs + (wn * 64 + j * 16 + l15) * 32 + quad * 8);
#pragma unroll
    for (int i = 0; i < 4; i++)
#pragma unroll
      for (int j = 0; j < 4; j++)
        acc[i][j] = __builtin_amdgcn_mfma_f32_16x16x32_bf16(af[i], bf[j], acc[i][j], 0, 0, 0);
  }

  // epilogue: C/D layout col=lane&15, row=quad*4+reg  (m89-verified)
  if (MODE == 0) {
    u16* q  = (u16*)out0;
    u16* k  = (u16*)out1;
    u16* vt = (u16*)out2;
#pragma unroll
    for (int i = 0; i < 4; i++) {
      int m = m0 + wm * 64 + i * 16 + quad * 4;   // + r below, never crosses b boundary
      int b = m >> 11, t = m & 2047;              // t multiple of 4
#pragma unroll
      for (int j = 0; j < 4; j++) {
        int f = n0 + wn * 64 + j * 16 + l15;
        int s = f >> 10, h = (f >> 6) & 15, d = f & 63;
        if (s == 2) {
          ushort4 pk;                              // keys t..t+3 of dim d
          pk.x = f2bf(acc[i][j][0]); pk.y = f2bf(acc[i][j][1]);
          pk.z = f2bf(acc[i][j][2]); pk.w = f2bf(acc[i][j][3]);
          int kt2  = t >> 6;
          int cw   = (t >> 3) & 7;                 // 8-key (16B) unit
          int pw   = cw ^ (d & 7);                 // bank-free b128 flash reads
          int half = (t >> 2) & 1;
          *(ushort4*)(vt + ((((size_t)(b * H_ + h) * 32 + kt2) * 64 + d) * 8 + pw) * 8 + half * 4) = pk;
        } else {
          u16* dst = (s == 0) ? q : k;
          float sc = (s == 0) ? SCFOLD : 1.0f;
#pragma unroll
          for (int r = 0; r < 4; r++)
            dst[(((size_t)(b * H_ + h)) * T_ + (t + r)) * DK_ + d] = f2bf(acc[i][j][r] * sc);
        }
      }
    }
  } else {
    float* outp = (float*)out0;
#pragma unroll
    for (int i = 0; i < 4; i++) {
      int m = m0 + wm * 64 + i * 16 + quad * 4;
#pragma unroll
      for (int j = 0; j < 4; j++) {
        int n = n0 + wn * 64 + j * 16 + l15;
#pragma unroll
        for (int r = 0; r < 4; r++)
          outp[(size_t)(m + r) * N + n] = acc[i][j][r];
      }
    }
  }
}

// ---------------- flash attention (K=32 PV, hoisted LDS reads) --------------
// grid (B*H, T/128), 256 thr. Wave w owns 32 Q-rows (2 x 16).
// S^T = K·Q^T via 16x16x32 with PERMUTED key->MFMA-row map: unit (u,h) loads
// K rows 32u + 8*(l15>>2) + 4h + (l15&3), so output reg r at lane (quad,l15)
// holds key 32u + 8*quad + 4h + r.  packexp(alpha)++packexp(beta) is then
// EXACTLY the K=32 A-fragment (k = quad*8 + j, keys 32u+8*quad..+7): PV and
// rowsum run as mfma_f32_16x16x32_bf16 (full-rate) with zero cross-lane ops.
// R12 schedule: all 8 K-frag reads + V(0) reads burst at tile top, then
// QK(0) -> QK(1) -> exp(0) -> read V(1) -> PV(0) -> exp(1) -> PV(1).
// Every ds_read is >=~150cy of issue distance from its consumer. No
// scheduling fences (R6 showed sched_barrier(0) costs ~12us of loop-carried
// overlap); single-barrier dbuf correctness rests on the compiler's
// vmcnt(0)+lgkmcnt(0) drain before s_barrier.
__global__ __launch_bounds__(256)
void flash_kernel(const u16* __restrict__ Q, const u16* __restrict__ Kg,
                  const u16* __restrict__ Vt, u16* __restrict__ AO) {
  __shared__ __attribute__((aligned(16))) u16 KVs[2][2][64 * 64];  // [buf][K/V]
  const int tid  = threadIdx.x;
  const int w    = tid >> 6, lane = tid & 63;
  const int quad = lane >> 4, l15 = lane & 15;
  const int bh   = blockIdx.x;
  const int q0   = blockIdx.y * 128;
  const u16* Qb = Q  + (size_t)bh * T_ * DK_;
  const u16* Kb = Kg + (size_t)bh * T_ * DK_;
  const u16* Vb = Vt + (size_t)bh * T_ * DK_;   // 32 tiles x 4096 u16, contiguous

  // Q fragments (B-operand of S^T = K·Q^T): lane n=q=l15 holds d=quad*8+j.
  short8 qf[2][2];
#pragma unroll
  for (int mi = 0; mi < 2; mi++)
#pragma unroll
    for (int ks = 0; ks < 2; ks++)
      qf[mi][ks] = *(const short8*)(Qb + (size_t)(q0 + w * 32 + mi * 16 + l15) * DK_ + ks * 32 + quad * 8);

  // ones A/B-fragment (bf16 1.0 x8) for K=32 rowsum MFMA
  short8 ones8;
#pragma unroll
  for (int z = 0; z < 8; z++) ones8[z] = (short)0x3F80;

  f32x4 O[2][4];       // rows q=quad*4+r, cols d=dj*16+l15 (C/D layout)
  f32x4 rowsum[2];
#pragma unroll
  for (int mi = 0; mi < 2; mi++) {
    rowsum[mi] = f32x4{0.f, 0.f, 0.f, 0.f};
#pragma unroll
    for (int dj = 0; dj < 4; dj++) O[mi][dj] = f32x4{0.f, 0.f, 0.f, 0.f};
  }

  const int swz = l15 & 7;
  const int NT  = T_ / 64;
  // kt-invariant LDS offsets (elements)
  const int koff0 = ((quad) ^ swz) * 8;            // d 0..31 K chunk
  const int koff1 = ((4 + quad) ^ swz) * 8;        // d 32..63 K chunk
  const int rA    = ((l15 >> 2) << 3) + (l15 & 3); // permuted key-row base
  const int voffu0 = ((quad) ^ swz) * 8;           // u=0 V chunk
  const int voffu1 = ((4 + quad) ^ swz) * 8;       // u=1 V chunk

  // stage tile kt into buffer b (async DMA). K: source-swizzled 16B chunks
  // with f(row) = (row&3)|(((row>>3)&1)<<2). V: linear copy (pre-swizzled).
  auto stage = [&](int kt, int b) {
#pragma unroll
    for (int c = 0; c < 2; ++c) {
      int s = c * 256 + tid;
      int row = s >> 3;
      int cc  = (s & 7) ^ ((row & 3) | (((row >> 3) & 1) << 2));
      gld_lds16(&KVs[b][0][(c * 256 + w * 64) * 8], Kb + (size_t)kt * 4096 + row * 64 + cc * 8);
      gld_lds16(&KVs[b][1][(c * 256 + w * 64) * 8], Vb + (size_t)kt * 4096 + s * 8);
    }
  };

  stage(0, 0);   // prologue

  for (int kt = 0; kt < NT; ++kt) {
    __syncthreads();               // DMA for buf[kt&1] landed during last iter
    if (kt + 1 < NT) stage(kt + 1, (kt + 1) & 1);   // hidden by compute below
    const u16* Ks = KVs[kt & 1][0];
    const u16* Vs = KVs[kt & 1][1];

    // ---- read burst: all K fragments (both units) + V fragments for u=0 ----
    const u16* krA0 = Ks + (rA)          * 64;   // u=0 h=0: keys 8*quad + r
    const u16* krB0 = Ks + (rA + 4)      * 64;   // u=0 h=1: keys 8*quad+4+r
    const u16* krA1 = Ks + (32 + rA)     * 64;   // u=1 h=0
    const u16* krB1 = Ks + (32 + rA + 4) * 64;   // u=1 h=1
    short8 ka0_0 = *(const short8*)(krA0 + koff0);
    short8 ka1_0 = *(const short8*)(krA0 + koff1);
    short8 kb0_0 = *(const short8*)(krB0 + koff0);
    short8 kb1_0 = *(const short8*)(krB0 + koff1);
    short8 ka0_1 = *(const short8*)(krA1 + koff0);
    short8 ka1_1 = *(const short8*)(krA1 + koff1);
    short8 kb0_1 = *(const short8*)(krB1 + koff0);
    short8 kb1_1 = *(const short8*)(krB1 + koff1);
    short8 vf0[4];
#pragma unroll
    for (int dj = 0; dj < 4; dj++)
      vf0[dj] = *(const short8*)(Vs + (dj * 16 + l15) * 64 + voffu0);

    // ---- QK(0): 8 MFMA ----
    f32x4 sA0c = f32x4{0.f, 0.f, 0.f, 0.f}, sA1c = sA0c, sB0c = sA0c, sB1c = sA0c;
    sA0c = __builtin_amdgcn_mfma_f32_16x16x32_bf16(ka0_0, qf[0][0], sA0c, 0, 0, 0);
    sA0c = __builtin_amdgcn_mfma_f32_16x16x32_bf16(ka1_0, qf[0][1], sA0c, 0, 0, 0);
    sA1c = __builtin_amdgcn_mfma_f32_16x16x32_bf16(ka0_0, qf[1][0], sA1c, 0, 0, 0);
    sA1c = __builtin_amdgcn_mfma_f32_16x16x32_bf16(ka1_0, qf[1][1], sA1c, 0, 0, 0);
    sB0c = __builtin_amdgcn_mfma_f32_16x16x32_bf16(kb0_0, qf[0][0], sB0c, 0, 0, 0);
    sB0c = __builtin_amdgcn_mfma_f32_16x16x32_bf16(kb1_0, qf[0][1], sB0c, 0, 0, 0);
    sB1c = __builtin_amdgcn_mfma_f32_16x16x32_bf16(kb0_0, qf[1][0], sB1c, 0, 0, 0);
    sB1c = __builtin_amdgcn_mfma_f32_16x16x32_bf16(kb1_0, qf[1][1], sB1c, 0, 0, 0);

    // ---- QK(1): 8 MFMA (K-frags read ~12 reads + 8 MFMAs ago) ----
    f32x4 sA0n = f32x4{0.f, 0.f, 0.f, 0.f}, sA1n = sA0n, sB0n = sA0n, sB1n = sA0n;
    sA0n = __builtin_amdgcn_mfma_f32_16x16x32_bf16(ka0_1, qf[0][0], sA0n, 0, 0, 0);
    sA0n = __builtin_amdgcn_mfma_f32_16x16x32_bf16(ka1_1, qf[0][1], sA0n, 0, 0, 0);
    sA1n = __builtin_amdgcn_mfma_f32_16x16x32_bf16(ka0_1, qf[1][0], sA1n, 0, 0, 0);
    sA1n = __builtin_amdgcn_mfma_f32_16x16x32_bf16(ka1_1, qf[1][1], sA1n, 0, 0, 0);
    sB0n = __builtin_amdgcn_mfma_f32_16x16x32_bf16(kb0_1, qf[0][0], sB0n, 0, 0, 0);
    sB0n = __builtin_amdgcn_mfma_f32_16x16x32_bf16(kb1_1, qf[0][1], sB0n, 0, 0, 0);
    sB1n = __builtin_amdgcn_mfma_f32_16x16x32_bf16(kb0_1, qf[1][0], sB1n, 0, 0, 0);
    sB1n = __builtin_amdgcn_mfma_f32_16x16x32_bf16(kb1_1, qf[1][1], sB1n, 0, 0, 0);

    // ---- exp/pack(0) (QK(0) results are 16 MFMAs old) ----
    short8 pa0 = cat44(packexp(sA0c), packexp(sB0c));
    short8 pa1 = cat44(packexp(sA1c), packexp(sB1c));

    // ---- read V fragments for u=1 (consumed after PV(0)+exp(1)) ----
    short8 vf1[4];
#pragma unroll
    for (int dj = 0; dj < 4; dj++)
      vf1[dj] = *(const short8*)(Vs + (dj * 16 + l15) * 64 + voffu1);

    // ---- rowsum(0) + PV(0): 10 MFMA (vf0 read at tile top) ----
    rowsum[0] = __builtin_amdgcn_mfma_f32_16x16x32_bf16(pa0, ones8, rowsum[0], 0, 0, 0);
    rowsum[1] = __builtin_amdgcn_mfma_f32_16x16x32_bf16(pa1, ones8, rowsum[1], 0, 0, 0);
#pragma unroll
    for (int dj = 0; dj < 4; dj++) {
      O[0][dj] = __builtin_amdgcn_mfma_f32_16x16x32_bf16(pa0, vf0[dj], O[0][dj], 0, 0, 0);
      O[1][dj] = __builtin_amdgcn_mfma_f32_16x16x32_bf16(pa1, vf0[dj], O[1][dj], 0, 0, 0);
    }

    // ---- exp/pack(1) ----
    short8 pb0 = cat44(packexp(sA0n), packexp(sB0n));
    short8 pb1 = cat44(packexp(sA1n), packexp(sB1n));

    // ---- rowsum(1) + PV(1): 10 MFMA (vf1 covered by PV(0)+exp(1)) ----
    rowsum[0] = __builtin_amdgcn_mfma_f32_16x16x32_bf16(pb0, ones8, rowsum[0], 0, 0, 0);
    rowsum[1] = __builtin_amdgcn_mfma_f32_16x16x32_bf16(pb1, ones8, rowsum[1], 0, 0, 0);
#pragma unroll
    for (int dj = 0; dj < 4; dj++) {
      O[0][dj] = __builtin_amdgcn_mfma_f32_16x16x32_bf16(pb0, vf1[dj], O[0][dj], 0, 0, 0);
      O[1][dj] = __builtin_amdgcn_mfma_f32_16x16x32_bf16(pb1, vf1[dj], O[1][dj], 0, 0, 0);
    }
  }

  // epilogue: rowsum[mi][r] holds the full key-sum for q-row quad*4+r
  const int b = bh >> 4, h = bh & 15;
#pragma unroll
  for (int mi = 0; mi < 2; mi++) {
#pragma unroll
    for (int r = 0; r < 4; r++) {
      float inv = 1.0f / rowsum[mi][r];
      int t = q0 + w * 32 + mi * 16 + quad * 4 + r;
#pragma unroll
      for (int dj = 0; dj < 4; dj++)
        AO[((size_t)(b * T_ + t)) * C_ + h * DK_ + dj * 16 + l15] = f2bf(O[mi][dj][r] * inv);
    }
  }
}

extern "C" void kernel_launch(void* const* d_in, const int* in_sizes, int n_in,
                              void* d_out, int out_size, void* d_ws, size_t ws_size,
                              hipStream_t stream) {
  const float* x    = (const float*)d_in[0];
  const float* wqkv = (const float*)d_in[1];
  const float* wo   = (const float*)d_in[2];

  char* p = (char*)d_ws;
  u16* xb    = (u16*)p; p += (size_t)M_ * C_ * 2;     // 16.8 MB
  u16* wqkvb = (u16*)p; p += (size_t)N1_ * C_ * 2;    //  6.3 MB
  u16* wob   = (u16*)p; p += (size_t)C_ * C_ * 2;     //  2.1 MB
  u16* qb    = (u16*)p; p += (size_t)M_ * C_ * 2;     // 16.8 MB  [B,H,T,64]
  u16* kb    = (u16*)p; p += (size_t)M_ * C_ * 2;     // 16.8 MB  [B,H,T,64]
  u16* vtb   = (u16*)p; p += (size_t)M_ * C_ * 2;     // 16.8 MB  tile-major swizzled
  u16* aob   = (u16*)p; p += (size_t)M_ * C_ * 2;     // 16.8 MB  [B,T,C]

  const int ncast = (M_ * C_ + N1_ * C_ + C_ * C_) / 4;
  cast_all<<<(ncast + 255) / 256, 256, 0, stream>>>(x, wqkv, wo, xb, wqkvb, wob);

  gemm_bt<0><<<dim3(N1_ / 128, M_ / 128), 256, 0, stream>>>(xb, wqkvb, qb, kb, vtb, C_, N1_);

  // grid (bh, qb): flat%8 == bh%8 -> all q-blocks of a head on one XCD
  flash_kernel<<<dim3(B_ * H_, T_ / 128), 256, 0, stream>>>(qb, kb, vtb, aob);

  gemm_bt<1><<<dim3(C_ / 128, M_ / 128), 256, 0, stream>>>(aob, wob, d_out, nullptr, nullptr, C_, C_);
}

// Round 9
// 257.394 us; speedup vs baseline: 1.0728x; 1.0542x over previous
//
#include <hip/hip_runtime.h>
#include <hip/hip_bf16.h>
#include <stdint.h>

// MHA fwd: x[4,2048,1024] fp32, w_qkv[3072,1024], w_o[1024,1024]
// bf16 MFMA pipeline: cast -> QKV gemm -> flash attention -> out gemm.
// R11: flash PV/rowsum on full-rate K=32 mfma via permuted QK key->row map.
// R12: flash LDS reads hoisted from consumers (ds_read latency critical path).
// R15: half-up rounding in packexp (1 op); no sched fences. flash=89.9us,
//      both checks pass.
// R16: GEMM BK 32->64 + XOR source swizzle on LDS staging. Mechanisms:
//  (a) barrier+vmcnt(0) drain (~300cy) amortized over 32 MFMAs not 16;
//  (b) old fragment read row*64B+quad*16B was 8-way bank conflict (m98:
//      1.7e7 conflicts on this layout); new read row*128B+((ks*4+quad)^
//      (l15&7))*16B + store cc=(s&7)^(row&7) replicates flash's K-pattern
//      which measures ZERO conflicts. Read row&7==l15&7 (wm*64, i*16 mult 8).

#define B_   4
#define T_   2048
#define H_   16
#define DK_  64
#define C_   1024
#define M_   (B_*T_)    // 8192 rows
#define N1_  (3*C_)     // 3072
#define LOG2E 1.44269504088896340736f
#define SCFOLD (0.125f * LOG2E)   // folded into q at QKV epilogue

using short8  = __attribute__((ext_vector_type(8))) short;
using short4v = __attribute__((ext_vector_type(4))) short;
using f32x4   = __attribute__((ext_vector_type(4))) float;
typedef unsigned short u16;

__device__ __forceinline__ u16 f2bf(float f) {       // RNE (used in epilogues)
  unsigned u = __float_as_uint(f);
  u += 0x7FFF + ((u >> 16) & 1);
  return (u16)(u >> 16);
}

// exp2 + round-half-up-to-bf16 + pack 4 floats -> short4v: 4 exp + 4 add +
// 2 perm. u += 0x8000 before hi16 extraction = round-to-nearest (ties up):
// unbiased in practice, 1 VALU op/value. NaN-safe: exp2 outputs are positive
// normals; +0x8000 cannot carry into NaN/inf for values < 2^127.
__device__ __forceinline__ short4v packexp(f32x4 s) {
  unsigned u0 = __float_as_uint(__builtin_amdgcn_exp2f(s[0])) + 0x8000u;
  unsigned u1 = __float_as_uint(__builtin_amdgcn_exp2f(s[1])) + 0x8000u;
  unsigned u2 = __float_as_uint(__builtin_amdgcn_exp2f(s[2])) + 0x8000u;
  unsigned u3 = __float_as_uint(__builtin_amdgcn_exp2f(s[3])) + 0x8000u;
  union { unsigned w[2]; short4v s4; } cv;
  cv.w[0] = __builtin_amdgcn_perm(u1, u0, 0x07060302);  // {hi16(u1),hi16(u0)}
  cv.w[1] = __builtin_amdgcn_perm(u3, u2, 0x07060302);  // {hi16(u3),hi16(u2)}
  return cv.s4;
}

__device__ __forceinline__ short8 cat44(short4v a, short4v b) {
  return __builtin_shufflevector(a, b, 0, 1, 2, 3, 4, 5, 6, 7);
}

// async global->LDS, 16B per lane; lds ptr is wave-uniform base, HW adds lane*16
__device__ __forceinline__ void gld_lds16(void* lds, const void* g) {
  __builtin_amdgcn_global_load_lds(
      (__attribute__((address_space(1))) void*)(g),
      (__attribute__((address_space(3))) void*)(lds), 16, 0, 0);
}

// ---------------- fp32 -> bf16 cast (all three tensors, one launch) ----------
__global__ void cast_all(const float* __restrict__ x, const float* __restrict__ wq,
                         const float* __restrict__ wo, u16* __restrict__ xb,
                         u16* __restrict__ wqb, u16* __restrict__ wob) {
  const int nx = M_ * C_ / 4, nq = N1_ * C_ / 4;
  int i = blockIdx.x * blockDim.x + threadIdx.x;
  const float* src; u16* dst; int j;
  if (i < nx)            { src = x;  dst = xb;  j = i; }
  else if (i < nx + nq)  { src = wq; dst = wqb; j = i - nx; }
  else                   { src = wo; dst = wob; j = i - nx - nq; }
  float4 v = ((const float4*)src)[j];
  ushort4 o;
  o.x = f2bf(v.x); o.y = f2bf(v.y); o.z = f2bf(v.z); o.w = f2bf(v.w);
  ((ushort4*)dst)[j] = o;
}

// ---------------- BT GEMM: C[m,n] = sum_k A[m,k]*B[n,k] ----------------
// 128x128 tile, BK=64 (R16), 4 waves in 2x2, each wave 64x64 (4x4 MFMA
// 16x16x32, 2 K-substeps). LDS staged via gld_lds16 with XOR source swizzle:
// store chunk cc=(s&7)^(row&7); read slot (ks*4+quad)^(l15&7) -> 2 lanes/bank
// group (conflict-free, flash-K-proven pattern). One barrier pair per 64 K.
// T1 XCD-aware block swizzle (bijective, nwg%8==0 for both launches).
// MODE 0: epilogue scatters qkv -> q (pre-scaled), k, V tile-major swizzled.
// MODE 1: epilogue writes fp32 C row-major [M,N]
template <int MODE>
__global__ __launch_bounds__(256)
void gemm_bt(const u16* __restrict__ A, const u16* __restrict__ Bm,
             void* __restrict__ out0, void* __restrict__ out1, void* __restrict__ out2,
             int K, int N) {
  __shared__ __attribute__((aligned(16))) u16 As[128 * 64];
  __shared__ __attribute__((aligned(16))) u16 Bs[128 * 64];
  const int tid  = threadIdx.x;
  const int w    = tid >> 6, lane = tid & 63;
  const int quad = lane >> 4, l15 = lane & 15;
  const int wm   = w >> 1, wn = w & 1;

  // XCD swizzle: launch order round-robins XCDs; remap so XCD i owns tiles
  // [i*cpx, (i+1)*cpx) in n-fastest order (T1; valid since nwg % 8 == 0).
  const int nxb = gridDim.x, nwg = nxb * gridDim.y;
  int flat = blockIdx.y * nxb + blockIdx.x;
  if ((nwg & 7) == 0) flat = (flat & 7) * (nwg >> 3) + (flat >> 3);
  const int m0 = (flat / nxb) * 128, n0 = (flat % nxb) * 128;

  f32x4 acc[4][4];
#pragma unroll
  for (int i = 0; i < 4; i++)
#pragma unroll
    for (int j = 0; j < 4; j++) acc[i][j] = f32x4{0.f, 0.f, 0.f, 0.f};

  const int xr = l15 & 7;          // read-side xor (== row&7 for frag rows)
  const int nkt = K >> 6;
  for (int kt = 0; kt < nkt; ++kt) {
    __syncthreads();
    // stage A,B tiles: 128x64 bf16 = 16KB each = 1024 chunks of 16B.
    // source-swizzled: chunk cc = (s&7) ^ (row&7) so LDS slot u holds
    // data chunk u^(row&7); read with the same xor recovers it.
#pragma unroll
    for (int c = 0; c < 4; ++c) {
      int s = c * 256 + tid;
      int row = s >> 3;
      int cc  = (s & 7) ^ (row & 7);
      gld_lds16(As + (c * 256 + w * 64) * 8, A  + (size_t)(m0 + row) * K + kt * 64 + cc * 8);
      gld_lds16(Bs + (c * 256 + w * 64) * 8, Bm + (size_t)(n0 + row) * K + kt * 64 + cc * 8);
    }
    __syncthreads();
#pragma unroll
    for (int ks = 0; ks < 2; ++ks) {
      short8 af[4], bf[4];
#pragma unroll
      for (int i = 0; i < 4; i++)
        af[i] = *(const short8*)(As + (wm * 64 + i * 16 + l15) * 64 + (((ks << 2) | quad) ^ xr) * 8);
#pragma unroll
      for (int j = 0; j < 4; j++)
        bf[j] = *(const short8*)(Bs + (wn * 64 + j * 16 + l15) * 64 + (((ks << 2) | quad) ^ xr) * 8);
#pragma unroll
      for (int i = 0; i < 4; i++)
#pragma unroll
        for (int j = 0; j < 4; j++)
          acc[i][j] = __builtin_amdgcn_mfma_f32_16x16x32_bf16(af[i], bf[j], acc[i][j], 0, 0, 0);
    }
  }

  // epilogue: C/D layout col=lane&15, row=quad*4+reg  (m89-verified)
  if (MODE == 0) {
    u16* q  = (u16*)out0;
    u16* k  = (u16*)out1;
    u16* vt = (u16*)out2;
#pragma unroll
    for (int i = 0; i < 4; i++) {
      int m = m0 + wm * 64 + i * 16 + quad * 4;   // + r below, never crosses b boundary
      int b = m >> 11, t = m & 2047;              // t multiple of 4
#pragma unroll
      for (int j = 0; j < 4; j++) {
        int f = n0 + wn * 64 + j * 16 + l15;
        int s = f >> 10, h = (f >> 6) & 15, d = f & 63;
        if (s == 2) {
          ushort4 pk;                              // keys t..t+3 of dim d
          pk.x = f2bf(acc[i][j][0]); pk.y = f2bf(acc[i][j][1]);
          pk.z = f2bf(acc[i][j][2]); pk.w = f2bf(acc[i][j][3]);
          int kt2  = t >> 6;
          int cw   = (t >> 3) & 7;                 // 8-key (16B) unit
          int pw   = cw ^ (d & 7);                 // bank-free b128 flash reads
          int half = (t >> 2) & 1;
          *(ushort4*)(vt + ((((size_t)(b * H_ + h) * 32 + kt2) * 64 + d) * 8 + pw) * 8 + half * 4) = pk;
        } else {
          u16* dst = (s == 0) ? q : k;
          float sc = (s == 0) ? SCFOLD : 1.0f;
#pragma unroll
          for (int r = 0; r < 4; r++)
            dst[(((size_t)(b * H_ + h)) * T_ + (t + r)) * DK_ + d] = f2bf(acc[i][j][r] * sc);
        }
      }
    }
  } else {
    float* outp = (float*)out0;
#pragma unroll
    for (int i = 0; i < 4; i++) {
      int m = m0 + wm * 64 + i * 16 + quad * 4;
#pragma unroll
      for (int j = 0; j < 4; j++) {
        int n = n0 + wn * 64 + j * 16 + l15;
#pragma unroll
        for (int r = 0; r < 4; r++)
          outp[(size_t)(m + r) * N + n] = acc[i][j][r];
      }
    }
  }
}

// ---------------- flash attention (K=32 PV, hoisted LDS reads) --------------
// grid (B*H, T/128), 256 thr. Wave w owns 32 Q-rows (2 x 16).
// S^T = K·Q^T via 16x16x32 with PERMUTED key->MFMA-row map: unit (u,h) loads
// K rows 32u + 8*(l15>>2) + 4h + (l15&3), so output reg r at lane (quad,l15)
// holds key 32u + 8*quad + 4h + r.  packexp(alpha)++packexp(beta) is then
// EXACTLY the K=32 A-fragment (k = quad*8 + j, keys 32u+8*quad..+7): PV and
// rowsum run as mfma_f32_16x16x32_bf16 (full-rate) with zero cross-lane ops.
// R12 schedule: all 8 K-frag reads + V(0) reads burst at tile top, then
// QK(0) -> QK(1) -> exp(0) -> read V(1) -> PV(0) -> exp(1) -> PV(1).
// Every ds_read is >=~150cy of issue distance from its consumer. No
// scheduling fences (R6: sched_barrier(0) costs ~12us of loop-carried
// overlap); single-barrier dbuf correctness rests on the compiler's
// vmcnt(0)+lgkmcnt(0) drain before s_barrier.
__global__ __launch_bounds__(256)
void flash_kernel(const u16* __restrict__ Q, const u16* __restrict__ Kg,
                  const u16* __restrict__ Vt, u16* __restrict__ AO) {
  __shared__ __attribute__((aligned(16))) u16 KVs[2][2][64 * 64];  // [buf][K/V]
  const int tid  = threadIdx.x;
  const int w    = tid >> 6, lane = tid & 63;
  const int quad = lane >> 4, l15 = lane & 15;
  const int bh   = blockIdx.x;
  const int q0   = blockIdx.y * 128;
  const u16* Qb = Q  + (size_t)bh * T_ * DK_;
  const u16* Kb = Kg + (size_t)bh * T_ * DK_;
  const u16* Vb = Vt + (size_t)bh * T_ * DK_;   // 32 tiles x 4096 u16, contiguous

  // Q fragments (B-operand of S^T = K·Q^T): lane n=q=l15 holds d=quad*8+j.
  short8 qf[2][2];
#pragma unroll
  for (int mi = 0; mi < 2; mi++)
#pragma unroll
    for (int ks = 0; ks < 2; ks++)
      qf[mi][ks] = *(const short8*)(Qb + (size_t)(q0 + w * 32 + mi * 16 + l15) * DK_ + ks * 32 + quad * 8);

  // ones A/B-fragment (bf16 1.0 x8) for K=32 rowsum MFMA
  short8 ones8;
#pragma unroll
  for (int z = 0; z < 8; z++) ones8[z] = (short)0x3F80;

  f32x4 O[2][4];       // rows q=quad*4+r, cols d=dj*16+l15 (C/D layout)
  f32x4 rowsum[2];
#pragma unroll
  for (int mi = 0; mi < 2; mi++) {
    rowsum[mi] = f32x4{0.f, 0.f, 0.f, 0.f};
#pragma unroll
    for (int dj = 0; dj < 4; dj++) O[mi][dj] = f32x4{0.f, 0.f, 0.f, 0.f};
  }

  const int swz = l15 & 7;
  const int NT  = T_ / 64;
  // kt-invariant LDS offsets (elements)
  const int koff0 = ((quad) ^ swz) * 8;            // d 0..31 K chunk
  const int koff1 = ((4 + quad) ^ swz) * 8;        // d 32..63 K chunk
  const int rA    = ((l15 >> 2) << 3) + (l15 & 3); // permuted key-row base
  const int voffu0 = ((quad) ^ swz) * 8;           // u=0 V chunk
  const int voffu1 = ((4 + quad) ^ swz) * 8;       // u=1 V chunk

  // stage tile kt into buffer b (async DMA). K: source-swizzled 16B chunks
  // with f(row) = (row&3)|(((row>>3)&1)<<2). V: linear copy (pre-swizzled).
  auto stage = [&](int kt, int b) {
#pragma unroll
    for (int c = 0; c < 2; ++c) {
      int s = c * 256 + tid;
      int row = s >> 3;
      int cc  = (s & 7) ^ ((row & 3) | (((row >> 3) & 1) << 2));
      gld_lds16(&KVs[b][0][(c * 256 + w * 64) * 8], Kb + (size_t)kt * 4096 + row * 64 + cc * 8);
      gld_lds16(&KVs[b][1][(c * 256 + w * 64) * 8], Vb + (size_t)kt * 4096 + s * 8);
    }
  };

  stage(0, 0);   // prologue

  for (int kt = 0; kt < NT; ++kt) {
    __syncthreads();               // DMA for buf[kt&1] landed during last iter
    if (kt + 1 < NT) stage(kt + 1, (kt + 1) & 1);   // hidden by compute below
    const u16* Ks = KVs[kt & 1][0];
    const u16* Vs = KVs[kt & 1][1];

    // ---- read burst: all K fragments (both units) + V fragments for u=0 ----
    const u16* krA0 = Ks + (rA)          * 64;   // u=0 h=0: keys 8*quad + r
    const u16* krB0 = Ks + (rA + 4)      * 64;   // u=0 h=1: keys 8*quad+4+r
    const u16* krA1 = Ks + (32 + rA)     * 64;   // u=1 h=0
    const u16* krB1 = Ks + (32 + rA + 4) * 64;   // u=1 h=1
    short8 ka0_0 = *(const short8*)(krA0 + koff0);
    short8 ka1_0 = *(const short8*)(krA0 + koff1);
    short8 kb0_0 = *(const short8*)(krB0 + koff0);
    short8 kb1_0 = *(const short8*)(krB0 + koff1);
    short8 ka0_1 = *(const short8*)(krA1 + koff0);
    short8 ka1_1 = *(const short8*)(krA1 + koff1);
    short8 kb0_1 = *(const short8*)(krB1 + koff0);
    short8 kb1_1 = *(const short8*)(krB1 + koff1);
    short8 vf0[4];
#pragma unroll
    for (int dj = 0; dj < 4; dj++)
      vf0[dj] = *(const short8*)(Vs + (dj * 16 + l15) * 64 + voffu0);

    // ---- QK(0): 8 MFMA ----
    f32x4 sA0c = f32x4{0.f, 0.f, 0.f, 0.f}, sA1c = sA0c, sB0c = sA0c, sB1c = sA0c;
    sA0c = __builtin_amdgcn_mfma_f32_16x16x32_bf16(ka0_0, qf[0][0], sA0c, 0, 0, 0);
    sA0c = __builtin_amdgcn_mfma_f32_16x16x32_bf16(ka1_0, qf[0][1], sA0c, 0, 0, 0);
    sA1c = __builtin_amdgcn_mfma_f32_16x16x32_bf16(ka0_0, qf[1][0], sA1c, 0, 0, 0);
    sA1c = __builtin_amdgcn_mfma_f32_16x16x32_bf16(ka1_0, qf[1][1], sA1c, 0, 0, 0);
    sB0c = __builtin_amdgcn_mfma_f32_16x16x32_bf16(kb0_0, qf[0][0], sB0c, 0, 0, 0);
    sB0c = __builtin_amdgcn_mfma_f32_16x16x32_bf16(kb1_0, qf[0][1], sB0c, 0, 0, 0);
    sB1c = __builtin_amdgcn_mfma_f32_16x16x32_bf16(kb0_0, qf[1][0], sB1c, 0, 0, 0);
    sB1c = __builtin_amdgcn_mfma_f32_16x16x32_bf16(kb1_0, qf[1][1], sB1c, 0, 0, 0);

    // ---- QK(1): 8 MFMA (K-frags read ~12 reads + 8 MFMAs ago) ----
    f32x4 sA0n = f32x4{0.f, 0.f, 0.f, 0.f}, sA1n = sA0n, sB0n = sA0n, sB1n = sA0n;
    sA0n = __builtin_amdgcn_mfma_f32_16x16x32_bf16(ka0_1, qf[0][0], sA0n, 0, 0, 0);
    sA0n = __builtin_amdgcn_mfma_f32_16x16x32_bf16(ka1_1, qf[0][1], sA0n, 0, 0, 0);
    sA1n = __builtin_amdgcn_mfma_f32_16x16x32_bf16(ka0_1, qf[1][0], sA1n, 0, 0, 0);
    sA1n = __builtin_amdgcn_mfma_f32_16x16x32_bf16(ka1_1, qf[1][1], sA1n, 0, 0, 0);
    sB0n = __builtin_amdgcn_mfma_f32_16x16x32_bf16(kb0_1, qf[0][0], sB0n, 0, 0, 0);
    sB0n = __builtin_amdgcn_mfma_f32_16x16x32_bf16(kb1_1, qf[0][1], sB0n, 0, 0, 0);
    sB1n = __builtin_amdgcn_mfma_f32_16x16x32_bf16(kb0_1, qf[1][0], sB1n, 0, 0, 0);
    sB1n = __builtin_amdgcn_mfma_f32_16x16x32_bf16(kb1_1, qf[1][1], sB1n, 0, 0, 0);

    // ---- exp/pack(0) (QK(0) results are 16 MFMAs old) ----
    short8 pa0 = cat44(packexp(sA0c), packexp(sB0c));
    short8 pa1 = cat44(packexp(sA1c), packexp(sB1c));

    // ---- read V fragments for u=1 (consumed after PV(0)+exp(1)) ----
    short8 vf1[4];
#pragma unroll
    for (int dj = 0; dj < 4; dj++)
      vf1[dj] = *(const short8*)(Vs + (dj * 16 + l15) * 64 + voffu1);

    // ---- rowsum(0) + PV(0): 10 MFMA (vf0 read at tile top) ----
    rowsum[0] = __builtin_amdgcn_mfma_f32_16x16x32_bf16(pa0, ones8, rowsum[0], 0, 0, 0);
    rowsum[1] = __builtin_amdgcn_mfma_f32_16x16x32_bf16(pa1, ones8, rowsum[1], 0, 0, 0);
#pragma unroll
    for (int dj = 0; dj < 4; dj++) {
      O[0][dj] = __builtin_amdgcn_mfma_f32_16x16x32_bf16(pa0, vf0[dj], O[0][dj], 0, 0, 0);
      O[1][dj] = __builtin_amdgcn_mfma_f32_16x16x32_bf16(pa1, vf0[dj], O[1][dj], 0, 0, 0);
    }

    // ---- exp/pack(1) ----
    short8 pb0 = cat44(packexp(sA0n), packexp(sB0n));
    short8 pb1 = cat44(packexp(sA1n), packexp(sB1n));

    // ---- rowsum(1) + PV(1): 10 MFMA (vf1 covered by PV(0)+exp(1)) ----
    rowsum[0] = __builtin_amdgcn_mfma_f32_16x16x32_bf16(pb0, ones8, rowsum[0], 0, 0, 0);
    rowsum[1] = __builtin_amdgcn_mfma_f32_16x16x32_bf16(pb1, ones8, rowsum[1], 0, 0, 0);
#pragma unroll
    for (int dj = 0; dj < 4; dj++) {
      O[0][dj] = __builtin_amdgcn_mfma_f32_16x16x32_bf16(pb0, vf1[dj], O[0][dj], 0, 0, 0);
      O[1][dj] = __builtin_amdgcn_mfma_f32_16x16x32_bf16(pb1, vf1[dj], O[1][dj], 0, 0, 0);
    }
  }

  // epilogue: rowsum[mi][r] holds the full key-sum for q-row quad*4+r
  const int b = bh >> 4, h = bh & 15;
#pragma unroll
  for (int mi = 0; mi < 2; mi++) {
#pragma unroll
    for (int r = 0; r < 4; r++) {
      float inv = 1.0f / rowsum[mi][r];
      int t = q0 + w * 32 + mi * 16 + quad * 4 + r;
#pragma unroll
      for (int dj = 0; dj < 4; dj++)
        AO[((size_t)(b * T_ + t)) * C_ + h * DK_ + dj * 16 + l15] = f2bf(O[mi][dj][r] * inv);
    }
  }
}

extern "C" void kernel_launch(void* const* d_in, const int* in_sizes, int n_in,
                              void* d_out, int out_size, void* d_ws, size_t ws_size,
                              hipStream_t stream) {
  const float* x    = (const float*)d_in[0];
  const float* wqkv = (const float*)d_in[1];
  const float* wo   = (const float*)d_in[2];

  char* p = (char*)d_ws;
  u16* xb    = (u16*)p; p += (size_t)M_ * C_ * 2;     // 16.8 MB
  u16* wqkvb = (u16*)p; p += (size_t)N1_ * C_ * 2;    //  6.3 MB
  u16* wob   = (u16*)p; p += (size_t)C_ * C_ * 2;     //  2.1 MB
  u16* qb    = (u16*)p; p += (size_t)M_ * C_ * 2;     // 16.8 MB  [B,H,T,64]
  u16* kb    = (u16*)p; p += (size_t)M_ * C_ * 2;     // 16.8 MB  [B,H,T,64]
  u16* vtb   = (u16*)p; p += (size_t)M_ * C_ * 2;     // 16.8 MB  tile-major swizzled
  u16* aob   = (u16*)p; p += (size_t)M_ * C_ * 2;     // 16.8 MB  [B,T,C]

  const int ncast = (M_ * C_ + N1_ * C_ + C_ * C_) / 4;
  cast_all<<<(ncast + 255) / 256, 256, 0, stream>>>(x, wqkv, wo, xb, wqkvb, wob);

  gemm_bt<0><<<dim3(N1_ / 128, M_ / 128), 256, 0, stream>>>(xb, wqkvb, qb, kb, vtb, C_, N1_);

  // grid (bh, qb): flat%8 == bh%8 -> all q-blocks of a head on one XCD
  flash_kernel<<<dim3(B_ * H_, T_ / 128), 256, 0, stream>>>(qb, kb, vtb, aob);

  gemm_bt<1><<<dim3(C_ / 128, M_ / 128), 256, 0, stream>>>(aob, wob, d_out, nullptr, nullptr, C_, C_);
}

// Round 10
// 255.302 us; speedup vs baseline: 1.0816x; 1.0082x over previous
//
#include <hip/hip_runtime.h>
#include <hip/hip_bf16.h>
#include <stdint.h>

// MHA fwd: x[4,2048,1024] fp32, w_qkv[3072,1024], w_o[1024,1024]
// bf16 MFMA pipeline: cast -> QKV gemm -> flash attention -> out gemm.
// R11: flash PV/rowsum on full-rate K=32 mfma via permuted QK key->row map.
// R12: flash LDS reads hoisted from consumers (ds_read latency critical path).
// R15: half-up rounding in packexp; no sched fences. flash=86.7us.
// R16: GEMM BK=64 + XOR source swizzle (conflict-free reads). total 257.4.
// R17: GEMM LDS double-buffer, single barrier/iter (flash's proven staging
// structure). Old loop was barrier->stage->BARRIER(vmcnt0 drain)->compute:
// every iter exposed full DMA latency (~200-500cy) vs ~155cy MFMA -> ~25-35%
// MFMA duty = the ~600TF GEMM plateau. New loop: barrier -> stage(t+1 into
// buf^1) -> compute(buf). DMA flies under compute; drain before NEXT barrier
// covers it (identical reasoning to flash, which measures correct + fast).
// LDS 64KB/block -> 2 blocks/CU (flash's working occupancy class).

#define B_   4
#define T_   2048
#define H_   16
#define DK_  64
#define C_   1024
#define M_   (B_*T_)    // 8192 rows
#define N1_  (3*C_)     // 3072
#define LOG2E 1.44269504088896340736f
#define SCFOLD (0.125f * LOG2E)   // folded into q at QKV epilogue

using short8  = __attribute__((ext_vector_type(8))) short;
using short4v = __attribute__((ext_vector_type(4))) short;
using f32x4   = __attribute__((ext_vector_type(4))) float;
typedef unsigned short u16;

__device__ __forceinline__ u16 f2bf(float f) {       // RNE (used in epilogues)
  unsigned u = __float_as_uint(f);
  u += 0x7FFF + ((u >> 16) & 1);
  return (u16)(u >> 16);
}

// exp2 + round-half-up-to-bf16 + pack 4 floats -> short4v: 4 exp + 4 add +
// 2 perm. u += 0x8000 before hi16 extraction = round-to-nearest (ties up):
// unbiased in practice, 1 VALU op/value. NaN-safe: exp2 outputs are positive
// normals; +0x8000 cannot carry into NaN/inf for values < 2^127.
__device__ __forceinline__ short4v packexp(f32x4 s) {
  unsigned u0 = __float_as_uint(__builtin_amdgcn_exp2f(s[0])) + 0x8000u;
  unsigned u1 = __float_as_uint(__builtin_amdgcn_exp2f(s[1])) + 0x8000u;
  unsigned u2 = __float_as_uint(__builtin_amdgcn_exp2f(s[2])) + 0x8000u;
  unsigned u3 = __float_as_uint(__builtin_amdgcn_exp2f(s[3])) + 0x8000u;
  union { unsigned w[2]; short4v s4; } cv;
  cv.w[0] = __builtin_amdgcn_perm(u1, u0, 0x07060302);  // {hi16(u1),hi16(u0)}
  cv.w[1] = __builtin_amdgcn_perm(u3, u2, 0x07060302);  // {hi16(u3),hi16(u2)}
  return cv.s4;
}

__device__ __forceinline__ short8 cat44(short4v a, short4v b) {
  return __builtin_shufflevector(a, b, 0, 1, 2, 3, 4, 5, 6, 7);
}

// async global->LDS, 16B per lane; lds ptr is wave-uniform base, HW adds lane*16
__device__ __forceinline__ void gld_lds16(void* lds, const void* g) {
  __builtin_amdgcn_global_load_lds(
      (__attribute__((address_space(1))) void*)(g),
      (__attribute__((address_space(3))) void*)(lds), 16, 0, 0);
}

// ---------------- fp32 -> bf16 cast (all three tensors, one launch) ----------
__global__ void cast_all(const float* __restrict__ x, const float* __restrict__ wq,
                         const float* __restrict__ wo, u16* __restrict__ xb,
                         u16* __restrict__ wqb, u16* __restrict__ wob) {
  const int nx = M_ * C_ / 4, nq = N1_ * C_ / 4;
  int i = blockIdx.x * blockDim.x + threadIdx.x;
  const float* src; u16* dst; int j;
  if (i < nx)            { src = x;  dst = xb;  j = i; }
  else if (i < nx + nq)  { src = wq; dst = wqb; j = i - nx; }
  else                   { src = wo; dst = wob; j = i - nx - nq; }
  float4 v = ((const float4*)src)[j];
  ushort4 o;
  o.x = f2bf(v.x); o.y = f2bf(v.y); o.z = f2bf(v.z); o.w = f2bf(v.w);
  ((ushort4*)dst)[j] = o;
}

// ---------------- BT GEMM: C[m,n] = sum_k A[m,k]*B[n,k] ----------------
// 128x128 tile, BK=64, 4 waves in 2x2, each wave 64x64 (4x4 MFMA 16x16x32,
// 2 K-substeps). R17: LDS double-buffered, ONE barrier per iter; stage(t+1)
// issued right after the barrier so its DMA is hidden under tile t's compute
// (flash-proven structure). XOR source swizzle: store cc=(s&7)^(row&7), read
// slot ((ks*4+quad)^(l15&7)) -> conflict-free (flash-K pattern, R16-verified).
// T1 XCD-aware block swizzle (bijective, nwg%8==0 for both launches).
// MODE 0: epilogue scatters qkv -> q (pre-scaled), k, V tile-major swizzled.
// MODE 1: epilogue writes fp32 C row-major [M,N]
template <int MODE>
__global__ __launch_bounds__(256)
void gemm_bt(const u16* __restrict__ A, const u16* __restrict__ Bm,
             void* __restrict__ out0, void* __restrict__ out1, void* __restrict__ out2,
             int K, int N) {
  __shared__ __attribute__((aligned(16))) u16 As[2][128 * 64];   // 2 x 16KB
  __shared__ __attribute__((aligned(16))) u16 Bs[2][128 * 64];   // 2 x 16KB
  const int tid  = threadIdx.x;
  const int w    = tid >> 6, lane = tid & 63;
  const int quad = lane >> 4, l15 = lane & 15;
  const int wm   = w >> 1, wn = w & 1;

  // XCD swizzle: launch order round-robins XCDs; remap so XCD i owns tiles
  // [i*cpx, (i+1)*cpx) in n-fastest order (T1; valid since nwg % 8 == 0).
  const int nxb = gridDim.x, nwg = nxb * gridDim.y;
  int flat = blockIdx.y * nxb + blockIdx.x;
  if ((nwg & 7) == 0) flat = (flat & 7) * (nwg >> 3) + (flat >> 3);
  const int m0 = (flat / nxb) * 128, n0 = (flat % nxb) * 128;

  f32x4 acc[4][4];
#pragma unroll
  for (int i = 0; i < 4; i++)
#pragma unroll
    for (int j = 0; j < 4; j++) acc[i][j] = f32x4{0.f, 0.f, 0.f, 0.f};

  // stage tile kt into buffer b: 128x64 bf16 = 16KB each = 1024 chunks of
  // 16B; source-swizzled so LDS slot u of row holds data chunk u^(row&7).
  auto stageg = [&](int kt, int b) {
#pragma unroll
    for (int c = 0; c < 4; ++c) {
      int s = c * 256 + tid;
      int row = s >> 3;
      int cc  = (s & 7) ^ (row & 7);
      gld_lds16(As[b] + (c * 256 + w * 64) * 8, A  + (size_t)(m0 + row) * K + kt * 64 + cc * 8);
      gld_lds16(Bs[b] + (c * 256 + w * 64) * 8, Bm + (size_t)(n0 + row) * K + kt * 64 + cc * 8);
    }
  };

  const int xr = l15 & 7;          // read-side xor (== row&7 for frag rows)
  const int nkt = K >> 6;
  stageg(0, 0);                    // prologue
  for (int kt = 0; kt < nkt; ++kt) {
    __syncthreads();               // drain before barrier covers buf[kt&1] DMA
    if (kt + 1 < nkt) stageg(kt + 1, (kt + 1) & 1);  // hidden under compute
    const u16* Asb = As[kt & 1];
    const u16* Bsb = Bs[kt & 1];
#pragma unroll
    for (int ks = 0; ks < 2; ++ks) {
      short8 af[4], bf[4];
#pragma unroll
      for (int i = 0; i < 4; i++)
        af[i] = *(const short8*)(Asb + (wm * 64 + i * 16 + l15) * 64 + (((ks << 2) | quad) ^ xr) * 8);
#pragma unroll
      for (int j = 0; j < 4; j++)
        bf[j] = *(const short8*)(Bsb + (wn * 64 + j * 16 + l15) * 64 + (((ks << 2) | quad) ^ xr) * 8);
#pragma unroll
      for (int i = 0; i < 4; i++)
#pragma unroll
        for (int j = 0; j < 4; j++)
          acc[i][j] = __builtin_amdgcn_mfma_f32_16x16x32_bf16(af[i], bf[j], acc[i][j], 0, 0, 0);
    }
  }

  // epilogue: C/D layout col=lane&15, row=quad*4+reg  (m89-verified)
  if (MODE == 0) {
    u16* q  = (u16*)out0;
    u16* k  = (u16*)out1;
    u16* vt = (u16*)out2;
#pragma unroll
    for (int i = 0; i < 4; i++) {
      int m = m0 + wm * 64 + i * 16 + quad * 4;   // + r below, never crosses b boundary
      int b = m >> 11, t = m & 2047;              // t multiple of 4
#pragma unroll
      for (int j = 0; j < 4; j++) {
        int f = n0 + wn * 64 + j * 16 + l15;
        int s = f >> 10, h = (f >> 6) & 15, d = f & 63;
        if (s == 2) {
          ushort4 pk;                              // keys t..t+3 of dim d
          pk.x = f2bf(acc[i][j][0]); pk.y = f2bf(acc[i][j][1]);
          pk.z = f2bf(acc[i][j][2]); pk.w = f2bf(acc[i][j][3]);
          int kt2  = t >> 6;
          int cw   = (t >> 3) & 7;                 // 8-key (16B) unit
          int pw   = cw ^ (d & 7);                 // bank-free b128 flash reads
          int half = (t >> 2) & 1;
          *(ushort4*)(vt + ((((size_t)(b * H_ + h) * 32 + kt2) * 64 + d) * 8 + pw) * 8 + half * 4) = pk;
        } else {
          u16* dst = (s == 0) ? q : k;
          float sc = (s == 0) ? SCFOLD : 1.0f;
#pragma unroll
          for (int r = 0; r < 4; r++)
            dst[(((size_t)(b * H_ + h)) * T_ + (t + r)) * DK_ + d] = f2bf(acc[i][j][r] * sc);
        }
      }
    }
  } else {
    float* outp = (float*)out0;
#pragma unroll
    for (int i = 0; i < 4; i++) {
      int m = m0 + wm * 64 + i * 16 + quad * 4;
#pragma unroll
      for (int j = 0; j < 4; j++) {
        int n = n0 + wn * 64 + j * 16 + l15;
#pragma unroll
        for (int r = 0; r < 4; r++)
          outp[(size_t)(m + r) * N + n] = acc[i][j][r];
      }
    }
  }
}

// ---------------- flash attention (K=32 PV, hoisted LDS reads) --------------
// grid (B*H, T/128), 256 thr. Wave w owns 32 Q-rows (2 x 16).
// S^T = K·Q^T via 16x16x32 with PERMUTED key->MFMA-row map: unit (u,h) loads
// K rows 32u + 8*(l15>>2) + 4h + (l15&3), so output reg r at lane (quad,l15)
// holds key 32u + 8*quad + 4h + r.  packexp(alpha)++packexp(beta) is then
// EXACTLY the K=32 A-fragment (k = quad*8 + j, keys 32u+8*quad..+7): PV and
// rowsum run as mfma_f32_16x16x32_bf16 (full-rate) with zero cross-lane ops.
// R12 schedule: all 8 K-frag reads + V(0) reads burst at tile top, then
// QK(0) -> QK(1) -> exp(0) -> read V(1) -> PV(0) -> exp(1) -> PV(1).
// Every ds_read is >=~150cy of issue distance from its consumer. No
// scheduling fences (R6: sched_barrier(0) costs ~12us of loop-carried
// overlap); single-barrier dbuf correctness rests on the compiler's
// vmcnt(0)+lgkmcnt(0) drain before s_barrier.
__global__ __launch_bounds__(256)
void flash_kernel(const u16* __restrict__ Q, const u16* __restrict__ Kg,
                  const u16* __restrict__ Vt, u16* __restrict__ AO) {
  __shared__ __attribute__((aligned(16))) u16 KVs[2][2][64 * 64];  // [buf][K/V]
  const int tid  = threadIdx.x;
  const int w    = tid >> 6, lane = tid & 63;
  const int quad = lane >> 4, l15 = lane & 15;
  const int bh   = blockIdx.x;
  const int q0   = blockIdx.y * 128;
  const u16* Qb = Q  + (size_t)bh * T_ * DK_;
  const u16* Kb = Kg + (size_t)bh * T_ * DK_;
  const u16* Vb = Vt + (size_t)bh * T_ * DK_;   // 32 tiles x 4096 u16, contiguous

  // Q fragments (B-operand of S^T = K·Q^T): lane n=q=l15 holds d=quad*8+j.
  short8 qf[2][2];
#pragma unroll
  for (int mi = 0; mi < 2; mi++)
#pragma unroll
    for (int ks = 0; ks < 2; ks++)
      qf[mi][ks] = *(const short8*)(Qb + (size_t)(q0 + w * 32 + mi * 16 + l15) * DK_ + ks * 32 + quad * 8);

  // ones A/B-fragment (bf16 1.0 x8) for K=32 rowsum MFMA
  short8 ones8;
#pragma unroll
  for (int z = 0; z < 8; z++) ones8[z] = (short)0x3F80;

  f32x4 O[2][4];       // rows q=quad*4+r, cols d=dj*16+l15 (C/D layout)
  f32x4 rowsum[2];
#pragma unroll
  for (int mi = 0; mi < 2; mi++) {
    rowsum[mi] = f32x4{0.f, 0.f, 0.f, 0.f};
#pragma unroll
    for (int dj = 0; dj < 4; dj++) O[mi][dj] = f32x4{0.f, 0.f, 0.f, 0.f};
  }

  const int swz = l15 & 7;
  const int NT  = T_ / 64;
  // kt-invariant LDS offsets (elements)
  const int koff0 = ((quad) ^ swz) * 8;            // d 0..31 K chunk
  const int koff1 = ((4 + quad) ^ swz) * 8;        // d 32..63 K chunk
  const int rA    = ((l15 >> 2) << 3) + (l15 & 3); // permuted key-row base
  const int voffu0 = ((quad) ^ swz) * 8;           // u=0 V chunk
  const int voffu1 = ((4 + quad) ^ swz) * 8;       // u=1 V chunk

  // stage tile kt into buffer b (async DMA). K: source-swizzled 16B chunks
  // with f(row) = (row&3)|(((row>>3)&1)<<2). V: linear copy (pre-swizzled).
  auto stage = [&](int kt, int b) {
#pragma unroll
    for (int c = 0; c < 2; ++c) {
      int s = c * 256 + tid;
      int row = s >> 3;
      int cc  = (s & 7) ^ ((row & 3) | (((row >> 3) & 1) << 2));
      gld_lds16(&KVs[b][0][(c * 256 + w * 64) * 8], Kb + (size_t)kt * 4096 + row * 64 + cc * 8);
      gld_lds16(&KVs[b][1][(c * 256 + w * 64) * 8], Vb + (size_t)kt * 4096 + s * 8);
    }
  };

  stage(0, 0);   // prologue

  for (int kt = 0; kt < NT; ++kt) {
    __syncthreads();               // DMA for buf[kt&1] landed during last iter
    if (kt + 1 < NT) stage(kt + 1, (kt + 1) & 1);   // hidden by compute below
    const u16* Ks = KVs[kt & 1][0];
    const u16* Vs = KVs[kt & 1][1];

    // ---- read burst: all K fragments (both units) + V fragments for u=0 ----
    const u16* krA0 = Ks + (rA)          * 64;   // u=0 h=0: keys 8*quad + r
    const u16* krB0 = Ks + (rA + 4)      * 64;   // u=0 h=1: keys 8*quad+4+r
    const u16* krA1 = Ks + (32 + rA)     * 64;   // u=1 h=0
    const u16* krB1 = Ks + (32 + rA + 4) * 64;   // u=1 h=1
    short8 ka0_0 = *(const short8*)(krA0 + koff0);
    short8 ka1_0 = *(const short8*)(krA0 + koff1);
    short8 kb0_0 = *(const short8*)(krB0 + koff0);
    short8 kb1_0 = *(const short8*)(krB0 + koff1);
    short8 ka0_1 = *(const short8*)(krA1 + koff0);
    short8 ka1_1 = *(const short8*)(krA1 + koff1);
    short8 kb0_1 = *(const short8*)(krB1 + koff0);
    short8 kb1_1 = *(const short8*)(krB1 + koff1);
    short8 vf0[4];
#pragma unroll
    for (int dj = 0; dj < 4; dj++)
      vf0[dj] = *(const short8*)(Vs + (dj * 16 + l15) * 64 + voffu0);

    // ---- QK(0): 8 MFMA ----
    f32x4 sA0c = f32x4{0.f, 0.f, 0.f, 0.f}, sA1c = sA0c, sB0c = sA0c, sB1c = sA0c;
    sA0c = __builtin_amdgcn_mfma_f32_16x16x32_bf16(ka0_0, qf[0][0], sA0c, 0, 0, 0);
    sA0c = __builtin_amdgcn_mfma_f32_16x16x32_bf16(ka1_0, qf[0][1], sA0c, 0, 0, 0);
    sA1c = __builtin_amdgcn_mfma_f32_16x16x32_bf16(ka0_0, qf[1][0], sA1c, 0, 0, 0);
    sA1c = __builtin_amdgcn_mfma_f32_16x16x32_bf16(ka1_0, qf[1][1], sA1c, 0, 0, 0);
    sB0c = __builtin_amdgcn_mfma_f32_16x16x32_bf16(kb0_0, qf[0][0], sB0c, 0, 0, 0);
    sB0c = __builtin_amdgcn_mfma_f32_16x16x32_bf16(kb1_0, qf[0][1], sB0c, 0, 0, 0);
    sB1c = __builtin_amdgcn_mfma_f32_16x16x32_bf16(kb0_0, qf[1][0], sB1c, 0, 0, 0);
    sB1c = __builtin_amdgcn_mfma_f32_16x16x32_bf16(kb1_0, qf[1][1], sB1c, 0, 0, 0);

    // ---- QK(1): 8 MFMA (K-frags read ~12 reads + 8 MFMAs ago) ----
    f32x4 sA0n = f32x4{0.f, 0.f, 0.f, 0.f}, sA1n = sA0n, sB0n = sA0n, sB1n = sA0n;
    sA0n = __builtin_amdgcn_mfma_f32_16x16x32_bf16(ka0_1, qf[0][0], sA0n, 0, 0, 0);
    sA0n = __builtin_amdgcn_mfma_f32_16x16x32_bf16(ka1_1, qf[0][1], sA0n, 0, 0, 0);
    sA1n = __builtin_amdgcn_mfma_f32_16x16x32_bf16(ka0_1, qf[1][0], sA1n, 0, 0, 0);
    sA1n = __builtin_amdgcn_mfma_f32_16x16x32_bf16(ka1_1, qf[1][1], sA1n, 0, 0, 0);
    sB0n = __builtin_amdgcn_mfma_f32_16x16x32_bf16(kb0_1, qf[0][0], sB0n, 0, 0, 0);
    sB0n = __builtin_amdgcn_mfma_f32_16x16x32_bf16(kb1_1, qf[0][1], sB0n, 0, 0, 0);
    sB1n = __builtin_amdgcn_mfma_f32_16x16x32_bf16(kb0_1, qf[1][0], sB1n, 0, 0, 0);
    sB1n = __builtin_amdgcn_mfma_f32_16x16x32_bf16(kb1_1, qf[1][1], sB1n, 0, 0, 0);

    // ---- exp/pack(0) (QK(0) results are 16 MFMAs old) ----
    short8 pa0 = cat44(packexp(sA0c), packexp(sB0c));
    short8 pa1 = cat44(packexp(sA1c), packexp(sB1c));

    // ---- read V fragments for u=1 (consumed after PV(0)+exp(1)) ----
    short8 vf1[4];
#pragma unroll
    for (int dj = 0; dj < 4; dj++)
      vf1[dj] = *(const short8*)(Vs + (dj * 16 + l15) * 64 + voffu1);

    // ---- rowsum(0) + PV(0): 10 MFMA (vf0 read at tile top) ----
    rowsum[0] = __builtin_amdgcn_mfma_f32_16x16x32_bf16(pa0, ones8, rowsum[0], 0, 0, 0);
    rowsum[1] = __builtin_amdgcn_mfma_f32_16x16x32_bf16(pa1, ones8, rowsum[1], 0, 0, 0);
#pragma unroll
    for (int dj = 0; dj < 4; dj++) {
      O[0][dj] = __builtin_amdgcn_mfma_f32_16x16x32_bf16(pa0, vf0[dj], O[0][dj], 0, 0, 0);
      O[1][dj] = __builtin_amdgcn_mfma_f32_16x16x32_bf16(pa1, vf0[dj], O[1][dj], 0, 0, 0);
    }

    // ---- exp/pack(1) ----
    short8 pb0 = cat44(packexp(sA0n), packexp(sB0n));
    short8 pb1 = cat44(packexp(sA1n), packexp(sB1n));

    // ---- rowsum(1) + PV(1): 10 MFMA (vf1 covered by PV(0)+exp(1)) ----
    rowsum[0] = __builtin_amdgcn_mfma_f32_16x16x32_bf16(pb0, ones8, rowsum[0], 0, 0, 0);
    rowsum[1] = __builtin_amdgcn_mfma_f32_16x16x32_bf16(pb1, ones8, rowsum[1], 0, 0, 0);
#pragma unroll
    for (int dj = 0; dj < 4; dj++) {
      O[0][dj] = __builtin_amdgcn_mfma_f32_16x16x32_bf16(pb0, vf1[dj], O[0][dj], 0, 0, 0);
      O[1][dj] = __builtin_amdgcn_mfma_f32_16x16x32_bf16(pb1, vf1[dj], O[1][dj], 0, 0, 0);
    }
  }

  // epilogue: rowsum[mi][r] holds the full key-sum for q-row quad*4+r
  const int b = bh >> 4, h = bh & 15;
#pragma unroll
  for (int mi = 0; mi < 2; mi++) {
#pragma unroll
    for (int r = 0; r < 4; r++) {
      float inv = 1.0f / rowsum[mi][r];
      int t = q0 + w * 32 + mi * 16 + quad * 4 + r;
#pragma unroll
      for (int dj = 0; dj < 4; dj++)
        AO[((size_t)(b * T_ + t)) * C_ + h * DK_ + dj * 16 + l15] = f2bf(O[mi][dj][r] * inv);
    }
  }
}

extern "C" void kernel_launch(void* const* d_in, const int* in_sizes, int n_in,
                              void* d_out, int out_size, void* d_ws, size_t ws_size,
                              hipStream_t stream) {
  const float* x    = (const float*)d_in[0];
  const float* wqkv = (const float*)d_in[1];
  const float* wo   = (const float*)d_in[2];

  char* p = (char*)d_ws;
  u16* xb    = (u16*)p; p += (size_t)M_ * C_ * 2;     // 16.8 MB
  u16* wqkvb = (u16*)p; p += (size_t)N1_ * C_ * 2;    //  6.3 MB
  u16* wob   = (u16*)p; p += (size_t)C_ * C_ * 2;     //  2.1 MB
  u16* qb    = (u16*)p; p += (size_t)M_ * C_ * 2;     // 16.8 MB  [B,H,T,64]
  u16* kb    = (u16*)p; p += (size_t)M_ * C_ * 2;     // 16.8 MB  [B,H,T,64]
  u16* vtb   = (u16*)p; p += (size_t)M_ * C_ * 2;     // 16.8 MB  tile-major swizzled
  u16* aob   = (u16*)p; p += (size_t)M_ * C_ * 2;     // 16.8 MB  [B,T,C]

  const int ncast = (M_ * C_ + N1_ * C_ + C_ * C_) / 4;
  cast_all<<<(ncast + 255) / 256, 256, 0, stream>>>(x, wqkv, wo, xb, wqkvb, wob);

  gemm_bt<0><<<dim3(N1_ / 128, M_ / 128), 256, 0, stream>>>(xb, wqkvb, qb, kb, vtb, C_, N1_);

  // grid (bh, qb): flat%8 == bh%8 -> all q-blocks of a head on one XCD
  flash_kernel<<<dim3(B_ * H_, T_ / 128), 256, 0, stream>>>(qb, kb, vtb, aob);

  gemm_bt<1><<<dim3(C_ / 128, M_ / 128), 256, 0, stream>>>(aob, wob, d_out, nullptr, nullptr, C_, C_);
}

// Round 12
// 254.762 us; speedup vs baseline: 1.0838x; 1.0021x over previous
//
#include <hip/hip_runtime.h>
#include <hip/hip_bf16.h>
#include <stdint.h>

// MHA fwd: x[4,2048,1024] fp32, w_qkv[3072,1024], w_o[1024,1024]
// bf16 MFMA pipeline: cast -> QKV gemm -> flash attention -> out gemm.
// R11: flash PV/rowsum on full-rate K=32 mfma via permuted QK key->row map.
// R12: flash LDS reads hoisted from consumers. R15: half-up packexp rounding.
// R16: GEMM BK=64 + XOR swizzle (-14us). R17: GEMM dbuf (-2us only -> staging
// DMA was NOT the bottleneck, matching learn_hip m99/m100's null).
// R18: LDS-bounce epilogues. GEMMs sit at ~460TF; with staging+banks fixed,
// the remaining fixed cost is the scatter epilogue: MODE0 wrote 48 SCALAR
// 2-byte stores/thread (q/k, 32B-granule coalescing, ~19M stores in QKV);
// MODE1 64 scalar dwords. Now: acc -> padded LDS tile (stride 136 u16,
// write conflicts <=2-way = free) -> coalesced 16B stores. s = n0>>10 is
// block-constant (128|1024): V-blocks keep their 8B-unit scatter (already
// fine). MODE1 bounces fp32 through 64KB LDS -> 16x dwordx4.
// R18b: desk-check fix — q/k store loop was emitting 1024 of 2048 chunks
// (c>>3/c&7 covered only 64 of 128 cols); now kk<8, row=c>>4, col8=c&15.

#define B_   4
#define T_   2048
#define H_   16
#define DK_  64
#define C_   1024
#define M_   (B_*T_)    // 8192 rows
#define N1_  (3*C_)     // 3072
#define LOG2E 1.44269504088896340736f
#define SCFOLD (0.125f * LOG2E)   // folded into q at QKV epilogue

using short8  = __attribute__((ext_vector_type(8))) short;
using short4v = __attribute__((ext_vector_type(4))) short;
using f32x4   = __attribute__((ext_vector_type(4))) float;
typedef unsigned short u16;

__device__ __forceinline__ u16 f2bf(float f) {       // RNE (used in epilogues)
  unsigned u = __float_as_uint(f);
  u += 0x7FFF + ((u >> 16) & 1);
  return (u16)(u >> 16);
}

// exp2 + round-half-up-to-bf16 + pack 4 floats -> short4v: 4 exp + 4 add +
// 2 perm. u += 0x8000 before hi16 extraction = round-to-nearest (ties up):
// unbiased in practice, 1 VALU op/value. NaN-safe: exp2 outputs are positive
// normals; +0x8000 cannot carry into NaN/inf for values < 2^127.
__device__ __forceinline__ short4v packexp(f32x4 s) {
  unsigned u0 = __float_as_uint(__builtin_amdgcn_exp2f(s[0])) + 0x8000u;
  unsigned u1 = __float_as_uint(__builtin_amdgcn_exp2f(s[1])) + 0x8000u;
  unsigned u2 = __float_as_uint(__builtin_amdgcn_exp2f(s[2])) + 0x8000u;
  unsigned u3 = __float_as_uint(__builtin_amdgcn_exp2f(s[3])) + 0x8000u;
  union { unsigned w[2]; short4v s4; } cv;
  cv.w[0] = __builtin_amdgcn_perm(u1, u0, 0x07060302);  // {hi16(u1),hi16(u0)}
  cv.w[1] = __builtin_amdgcn_perm(u3, u2, 0x07060302);  // {hi16(u3),hi16(u2)}
  return cv.s4;
}

__device__ __forceinline__ short8 cat44(short4v a, short4v b) {
  return __builtin_shufflevector(a, b, 0, 1, 2, 3, 4, 5, 6, 7);
}

// async global->LDS, 16B per lane; lds ptr is wave-uniform base, HW adds lane*16
__device__ __forceinline__ void gld_lds16(void* lds, const void* g) {
  __builtin_amdgcn_global_load_lds(
      (__attribute__((address_space(1))) void*)(g),
      (__attribute__((address_space(3))) void*)(lds), 16, 0, 0);
}

// ---------------- fp32 -> bf16 cast (all three tensors, one launch) ----------
__global__ void cast_all(const float* __restrict__ x, const float* __restrict__ wq,
                         const float* __restrict__ wo, u16* __restrict__ xb,
                         u16* __restrict__ wqb, u16* __restrict__ wob) {
  const int nx = M_ * C_ / 4, nq = N1_ * C_ / 4;
  int i = blockIdx.x * blockDim.x + threadIdx.x;
  const float* src; u16* dst; int j;
  if (i < nx)            { src = x;  dst = xb;  j = i; }
  else if (i < nx + nq)  { src = wq; dst = wqb; j = i - nx; }
  else                   { src = wo; dst = wob; j = i - nx - nq; }
  float4 v = ((const float4*)src)[j];
  ushort4 o;
  o.x = f2bf(v.x); o.y = f2bf(v.y); o.z = f2bf(v.z); o.w = f2bf(v.w);
  ((ushort4*)dst)[j] = o;
}

// ---------------- BT GEMM: C[m,n] = sum_k A[m,k]*B[n,k] ----------------
// 128x128 tile, BK=64, 4 waves in 2x2, each wave 64x64 (4x4 MFMA 16x16x32,
// 2 K-substeps). LDS double-buffered (R17), single barrier/iter. XOR source
// swizzle on staging: store cc=(s&7)^(row&7), read slot ((ks*4+quad)^(l15&7))
// -> conflict-free (R16-verified). T1 XCD block swizzle.
// R18 epilogues bounce through LDS (reusing the 64KB staging space) for
// coalesced 16B stores; V-blocks (s==2) keep the direct 8B-unit scatter.
template <int MODE>
__global__ __launch_bounds__(256)
void gemm_bt(const u16* __restrict__ A, const u16* __restrict__ Bm,
             void* __restrict__ out0, void* __restrict__ out1, void* __restrict__ out2,
             int K, int N) {
  __shared__ __attribute__((aligned(16))) u16 SMEM[4 * 128 * 64];  // 64KB
  u16* As0 = SMEM;
  u16* As1 = SMEM + 128 * 64;
  u16* Bs0 = SMEM + 2 * 128 * 64;
  u16* Bs1 = SMEM + 3 * 128 * 64;
  const int tid  = threadIdx.x;
  const int w    = tid >> 6, lane = tid & 63;
  const int quad = lane >> 4, l15 = lane & 15;
  const int wm   = w >> 1, wn = w & 1;

  // XCD swizzle: launch order round-robins XCDs; remap so XCD i owns tiles
  // [i*cpx, (i+1)*cpx) in n-fastest order (T1; valid since nwg % 8 == 0).
  const int nxb = gridDim.x, nwg = nxb * gridDim.y;
  int flat = blockIdx.y * nxb + blockIdx.x;
  if ((nwg & 7) == 0) flat = (flat & 7) * (nwg >> 3) + (flat >> 3);
  const int m0 = (flat / nxb) * 128, n0 = (flat % nxb) * 128;

  f32x4 acc[4][4];
#pragma unroll
  for (int i = 0; i < 4; i++)
#pragma unroll
    for (int j = 0; j < 4; j++) acc[i][j] = f32x4{0.f, 0.f, 0.f, 0.f};

  // stage tile kt into buffer b: 128x64 bf16 = 16KB each = 1024 chunks of
  // 16B; source-swizzled so LDS slot u of row holds data chunk u^(row&7).
  auto stageg = [&](int kt, int b) {
    u16* Ad = b ? As1 : As0;
    u16* Bd = b ? Bs1 : Bs0;
#pragma unroll
    for (int c = 0; c < 4; ++c) {
      int s = c * 256 + tid;
      int row = s >> 3;
      int cc  = (s & 7) ^ (row & 7);
      gld_lds16(Ad + (c * 256 + w * 64) * 8, A  + (size_t)(m0 + row) * K + kt * 64 + cc * 8);
      gld_lds16(Bd + (c * 256 + w * 64) * 8, Bm + (size_t)(n0 + row) * K + kt * 64 + cc * 8);
    }
  };

  const int xr = l15 & 7;          // read-side xor (== row&7 for frag rows)
  const int nkt = K >> 6;
  stageg(0, 0);                    // prologue
  for (int kt = 0; kt < nkt; ++kt) {
    __syncthreads();               // drain before barrier covers buf[kt&1] DMA
    if (kt + 1 < nkt) stageg(kt + 1, (kt + 1) & 1);  // hidden under compute
    const u16* Asb = (kt & 1) ? As1 : As0;
    const u16* Bsb = (kt & 1) ? Bs1 : Bs0;
#pragma unroll
    for (int ks = 0; ks < 2; ++ks) {
      short8 af[4], bf[4];
#pragma unroll
      for (int i = 0; i < 4; i++)
        af[i] = *(const short8*)(Asb + (wm * 64 + i * 16 + l15) * 64 + (((ks << 2) | quad) ^ xr) * 8);
#pragma unroll
      for (int j = 0; j < 4; j++)
        bf[j] = *(const short8*)(Bsb + (wn * 64 + j * 16 + l15) * 64 + (((ks << 2) | quad) ^ xr) * 8);
#pragma unroll
      for (int i = 0; i < 4; i++)
#pragma unroll
        for (int j = 0; j < 4; j++)
          acc[i][j] = __builtin_amdgcn_mfma_f32_16x16x32_bf16(af[i], bf[j], acc[i][j], 0, 0, 0);
    }
  }

  // epilogue: C/D layout col=lane&15, row=quad*4+reg  (m89-verified)
  if (MODE == 0) {
    const int sblk = n0 >> 10;                     // block-constant (128|1024)
    if (sblk == 2) {
      // V: direct scatter in 8B units (flash-ready tile-major swizzle)
      u16* vt = (u16*)out2;
#pragma unroll
      for (int i = 0; i < 4; i++) {
        int m = m0 + wm * 64 + i * 16 + quad * 4;
        int b = m >> 11, t = m & 2047;             // t multiple of 4
#pragma unroll
        for (int j = 0; j < 4; j++) {
          int f = n0 + wn * 64 + j * 16 + l15;
          int h = (f >> 6) & 15, d = f & 63;
          ushort4 pk;                              // keys t..t+3 of dim d
          pk.x = f2bf(acc[i][j][0]); pk.y = f2bf(acc[i][j][1]);
          pk.z = f2bf(acc[i][j][2]); pk.w = f2bf(acc[i][j][3]);
          int kt2  = t >> 6;
          int cw   = (t >> 3) & 7;                 // 8-key (16B) unit
          int pw   = cw ^ (d & 7);                 // bank-free b128 flash reads
          int half = (t >> 2) & 1;
          *(ushort4*)(vt + ((((size_t)(b * H_ + h) * 32 + kt2) * 64 + d) * 8 + pw) * 8 + half * 4) = pk;
        }
      }
    } else {
      // q/k: bounce through LDS (stride 136 u16 -> <=2-way write conflicts),
      // then coalesced 16B row-chunk stores (128 rows x 16 chunks = 2048).
      u16* dst = (sblk == 0) ? (u16*)out0 : (u16*)out1;
      const float sc = (sblk == 0) ? SCFOLD : 1.0f;
      u16* Ct = SMEM;                              // 128 x 136 u16 = 34.8KB
      __syncthreads();                             // staging reads all done
#pragma unroll
      for (int i = 0; i < 4; i++) {
        int rl = wm * 64 + i * 16 + quad * 4;
#pragma unroll
        for (int j = 0; j < 4; j++) {
          int cl = wn * 64 + j * 16 + l15;
#pragma unroll
          for (int r = 0; r < 4; r++)
            Ct[(rl + r) * 136 + cl] = f2bf(acc[i][j][r] * sc);
        }
      }
      __syncthreads();
      const int bb = m0 >> 11, t0 = m0 & 2047;
#pragma unroll
      for (int kk = 0; kk < 8; ++kk) {
        int c = kk * 256 + tid;                    // 0..2047 chunks of 8 u16
        int row = c >> 4, col8 = c & 15;
        int f = n0 + col8 * 8;
        int h = (f >> 6) & 15, d = f & 63;
        short8 vv = *(const short8*)(Ct + row * 136 + col8 * 8);
        *(short8*)(dst + (((size_t)(bb * H_ + h)) * T_ + (t0 + row)) * DK_ + d) = vv;
      }
    }
  } else {
    // fp32 out: bounce through LDS (64KB exactly), 16B dwordx4 stores.
    float* outp = (float*)out0;
    float* Cf = (float*)SMEM;                      // 128 x 128 f32
    __syncthreads();                               // staging reads all done
#pragma unroll
    for (int i = 0; i < 4; i++) {
      int rl = wm * 64 + i * 16 + quad * 4;
#pragma unroll
      for (int j = 0; j < 4; j++) {
        int cl = wn * 64 + j * 16 + l15;
#pragma unroll
        for (int r = 0; r < 4; r++)
          Cf[(rl + r) * 128 + cl] = acc[i][j][r];
      }
    }
    __syncthreads();
#pragma unroll
    for (int kk = 0; kk < 16; ++kk) {
      int c = kk * 256 + tid;                      // 0..4095 chunks of 4 f32
      int row = c >> 5, col4 = c & 31;
      float4 vv = *(const float4*)(Cf + row * 128 + col4 * 4);
      *(float4*)(outp + (size_t)(m0 + row) * N + n0 + col4 * 4) = vv;
    }
  }
}

// ---------------- flash attention (K=32 PV, hoisted LDS reads) --------------
// grid (B*H, T/128), 256 thr. Wave w owns 32 Q-rows (2 x 16).
// S^T = K·Q^T via 16x16x32 with PERMUTED key->MFMA-row map: unit (u,h) loads
// K rows 32u + 8*(l15>>2) + 4h + (l15&3), so output reg r at lane (quad,l15)
// holds key 32u + 8*quad + 4h + r.  packexp(alpha)++packexp(beta) is then
// EXACTLY the K=32 A-fragment (k = quad*8 + j, keys 32u+8*quad..+7): PV and
// rowsum run as mfma_f32_16x16x32_bf16 (full-rate) with zero cross-lane ops.
// R12 schedule: all 8 K-frag reads + V(0) reads burst at tile top, then
// QK(0) -> QK(1) -> exp(0) -> read V(1) -> PV(0) -> exp(1) -> PV(1).
// Every ds_read is >=~150cy of issue distance from its consumer. No
// scheduling fences (R6: sched_barrier(0) costs ~12us of loop-carried
// overlap); single-barrier dbuf correctness rests on the compiler's
// vmcnt(0)+lgkmcnt(0) drain before s_barrier.
__global__ __launch_bounds__(256)
void flash_kernel(const u16* __restrict__ Q, const u16* __restrict__ Kg,
                  const u16* __restrict__ Vt, u16* __restrict__ AO) {
  __shared__ __attribute__((aligned(16))) u16 KVs[2][2][64 * 64];  // [buf][K/V]
  const int tid  = threadIdx.x;
  const int w    = tid >> 6, lane = tid & 63;
  const int quad = lane >> 4, l15 = lane & 15;
  const int bh   = blockIdx.x;
  const int q0   = blockIdx.y * 128;
  const u16* Qb = Q  + (size_t)bh * T_ * DK_;
  const u16* Kb = Kg + (size_t)bh * T_ * DK_;
  const u16* Vb = Vt + (size_t)bh * T_ * DK_;   // 32 tiles x 4096 u16, contiguous

  // Q fragments (B-operand of S^T = K·Q^T): lane n=q=l15 holds d=quad*8+j.
  short8 qf[2][2];
#pragma unroll
  for (int mi = 0; mi < 2; mi++)
#pragma unroll
    for (int ks = 0; ks < 2; ks++)
      qf[mi][ks] = *(const short8*)(Qb + (size_t)(q0 + w * 32 + mi * 16 + l15) * DK_ + ks * 32 + quad * 8);

  // ones A/B-fragment (bf16 1.0 x8) for K=32 rowsum MFMA
  short8 ones8;
#pragma unroll
  for (int z = 0; z < 8; z++) ones8[z] = (short)0x3F80;

  f32x4 O[2][4];       // rows q=quad*4+r, cols d=dj*16+l15 (C/D layout)
  f32x4 rowsum[2];
#pragma unroll
  for (int mi = 0; mi < 2; mi++) {
    rowsum[mi] = f32x4{0.f, 0.f, 0.f, 0.f};
#pragma unroll
    for (int dj = 0; dj < 4; dj++) O[mi][dj] = f32x4{0.f, 0.f, 0.f, 0.f};
  }

  const int swz = l15 & 7;
  const int NT  = T_ / 64;
  // kt-invariant LDS offsets (elements)
  const int koff0 = ((quad) ^ swz) * 8;            // d 0..31 K chunk
  const int koff1 = ((4 + quad) ^ swz) * 8;        // d 32..63 K chunk
  const int rA    = ((l15 >> 2) << 3) + (l15 & 3); // permuted key-row base
  const int voffu0 = ((quad) ^ swz) * 8;           // u=0 V chunk
  const int voffu1 = ((4 + quad) ^ swz) * 8;       // u=1 V chunk

  // stage tile kt into buffer b (async DMA). K: source-swizzled 16B chunks
  // with f(row) = (row&3)|(((row>>3)&1)<<2). V: linear copy (pre-swizzled).
  auto stage = [&](int kt, int b) {
#pragma unroll
    for (int c = 0; c < 2; ++c) {
      int s = c * 256 + tid;
      int row = s >> 3;
      int cc  = (s & 7) ^ ((row & 3) | (((row >> 3) & 1) << 2));
      gld_lds16(&KVs[b][0][(c * 256 + w * 64) * 8], Kb + (size_t)kt * 4096 + row * 64 + cc * 8);
      gld_lds16(&KVs[b][1][(c * 256 + w * 64) * 8], Vb + (size_t)kt * 4096 + s * 8);
    }
  };

  stage(0, 0);   // prologue

  for (int kt = 0; kt < NT; ++kt) {
    __syncthreads();               // DMA for buf[kt&1] landed during last iter
    if (kt + 1 < NT) stage(kt + 1, (kt + 1) & 1);   // hidden by compute below
    const u16* Ks = KVs[kt & 1][0];
    const u16* Vs = KVs[kt & 1][1];

    // ---- read burst: all K fragments (both units) + V fragments for u=0 ----
    const u16* krA0 = Ks + (rA)          * 64;   // u=0 h=0: keys 8*quad + r
    const u16* krB0 = Ks + (rA + 4)      * 64;   // u=0 h=1: keys 8*quad+4+r
    const u16* krA1 = Ks + (32 + rA)     * 64;   // u=1 h=0
    const u16* krB1 = Ks + (32 + rA + 4) * 64;   // u=1 h=1
    short8 ka0_0 = *(const short8*)(krA0 + koff0);
    short8 ka1_0 = *(const short8*)(krA0 + koff1);
    short8 kb0_0 = *(const short8*)(krB0 + koff0);
    short8 kb1_0 = *(const short8*)(krB0 + koff1);
    short8 ka0_1 = *(const short8*)(krA1 + koff0);
    short8 ka1_1 = *(const short8*)(krA1 + koff1);
    short8 kb0_1 = *(const short8*)(krB1 + koff0);
    short8 kb1_1 = *(const short8*)(krB1 + koff1);
    short8 vf0[4];
#pragma unroll
    for (int dj = 0; dj < 4; dj++)
      vf0[dj] = *(const short8*)(Vs + (dj * 16 + l15) * 64 + voffu0);

    // ---- QK(0): 8 MFMA ----
    f32x4 sA0c = f32x4{0.f, 0.f, 0.f, 0.f}, sA1c = sA0c, sB0c = sA0c, sB1c = sA0c;
    sA0c = __builtin_amdgcn_mfma_f32_16x16x32_bf16(ka0_0, qf[0][0], sA0c, 0, 0, 0);
    sA0c = __builtin_amdgcn_mfma_f32_16x16x32_bf16(ka1_0, qf[0][1], sA0c, 0, 0, 0);
    sA1c = __builtin_amdgcn_mfma_f32_16x16x32_bf16(ka0_0, qf[1][0], sA1c, 0, 0, 0);
    sA1c = __builtin_amdgcn_mfma_f32_16x16x32_bf16(ka1_0, qf[1][1], sA1c, 0, 0, 0);
    sB0c = __builtin_amdgcn_mfma_f32_16x16x32_bf16(kb0_0, qf[0][0], sB0c, 0, 0, 0);
    sB0c = __builtin_amdgcn_mfma_f32_16x16x32_bf16(kb1_0, qf[0][1], sB0c, 0, 0, 0);
    sB1c = __builtin_amdgcn_mfma_f32_16x16x32_bf16(kb0_0, qf[1][0], sB1c, 0, 0, 0);
    sB1c = __builtin_amdgcn_mfma_f32_16x16x32_bf16(kb1_0, qf[1][1], sB1c, 0, 0, 0);

    // ---- QK(1): 8 MFMA (K-frags read ~12 reads + 8 MFMAs ago) ----
    f32x4 sA0n = f32x4{0.f, 0.f, 0.f, 0.f}, sA1n = sA0n, sB0n = sA0n, sB1n = sA0n;
    sA0n = __builtin_amdgcn_mfma_f32_16x16x32_bf16(ka0_1, qf[0][0], sA0n, 0, 0, 0);
    sA0n = __builtin_amdgcn_mfma_f32_16x16x32_bf16(ka1_1, qf[0][1], sA0n, 0, 0, 0);
    sA1n = __builtin_amdgcn_mfma_f32_16x16x32_bf16(ka0_1, qf[1][0], sA1n, 0, 0, 0);
    sA1n = __builtin_amdgcn_mfma_f32_16x16x32_bf16(ka1_1, qf[1][1], sA1n, 0, 0, 0);
    sB0n = __builtin_amdgcn_mfma_f32_16x16x32_bf16(kb0_1, qf[0][0], sB0n, 0, 0, 0);
    sB0n = __builtin_amdgcn_mfma_f32_16x16x32_bf16(kb1_1, qf[0][1], sB0n, 0, 0, 0);
    sB1n = __builtin_amdgcn_mfma_f32_16x16x32_bf16(kb0_1, qf[1][0], sB1n, 0, 0, 0);
    sB1n = __builtin_amdgcn_mfma_f32_16x16x32_bf16(kb1_1, qf[1][1], sB1n, 0, 0, 0);

    // ---- exp/pack(0) (QK(0) results are 16 MFMAs old) ----
    short8 pa0 = cat44(packexp(sA0c), packexp(sB0c));
    short8 pa1 = cat44(packexp(sA1c), packexp(sB1c));

    // ---- read V fragments for u=1 (consumed after PV(0)+exp(1)) ----
    short8 vf1[4];
#pragma unroll
    for (int dj = 0; dj < 4; dj++)
      vf1[dj] = *(const short8*)(Vs + (dj * 16 + l15) * 64 + voffu1);

    // ---- rowsum(0) + PV(0): 10 MFMA (vf0 read at tile top) ----
    rowsum[0] = __builtin_amdgcn_mfma_f32_16x16x32_bf16(pa0, ones8, rowsum[0], 0, 0, 0);
    rowsum[1] = __builtin_amdgcn_mfma_f32_16x16x32_bf16(pa1, ones8, rowsum[1], 0, 0, 0);
#pragma unroll
    for (int dj = 0; dj < 4; dj++) {
      O[0][dj] = __builtin_amdgcn_mfma_f32_16x16x32_bf16(pa0, vf0[dj], O[0][dj], 0, 0, 0);
      O[1][dj] = __builtin_amdgcn_mfma_f32_16x16x32_bf16(pa1, vf0[dj], O[1][dj], 0, 0, 0);
    }

    // ---- exp/pack(1) ----
    short8 pb0 = cat44(packexp(sA0n), packexp(sB0n));
    short8 pb1 = cat44(packexp(sA1n), packexp(sB1n));

    // ---- rowsum(1) + PV(1): 10 MFMA (vf1 covered by PV(0)+exp(1)) ----
    rowsum[0] = __builtin_amdgcn_mfma_f32_16x16x32_bf16(pb0, ones8, rowsum[0], 0, 0, 0);
    rowsum[1] = __builtin_amdgcn_mfma_f32_16x16x32_bf16(pb1, ones8, rowsum[1], 0, 0, 0);
#pragma unroll
    for (int dj = 0; dj < 4; dj++) {
      O[0][dj] = __builtin_amdgcn_mfma_f32_16x16x32_bf16(pb0, vf1[dj], O[0][dj], 0, 0, 0);
      O[1][dj] = __builtin_amdgcn_mfma_f32_16x16x32_bf16(pb1, vf1[dj], O[1][dj], 0, 0, 0);
    }
  }

  // epilogue: rowsum[mi][r] holds the full key-sum for q-row quad*4+r
  const int b = bh >> 4, h = bh & 15;
#pragma unroll
  for (int mi = 0; mi < 2; mi++) {
#pragma unroll
    for (int r = 0; r < 4; r++) {
      float inv = 1.0f / rowsum[mi][r];
      int t = q0 + w * 32 + mi * 16 + quad * 4 + r;
#pragma unroll
      for (int dj = 0; dj < 4; dj++)
        AO[((size_t)(b * T_ + t)) * C_ + h * DK_ + dj * 16 + l15] = f2bf(O[mi][dj][r] * inv);
    }
  }
}

extern "C" void kernel_launch(void* const* d_in, const int* in_sizes, int n_in,
                              void* d_out, int out_size, void* d_ws, size_t ws_size,
                              hipStream_t stream) {
  const float* x    = (const float*)d_in[0];
  const float* wqkv = (const float*)d_in[1];
  const float* wo   = (const float*)d_in[2];

  char* p = (char*)d_ws;
  u16* xb    = (u16*)p; p += (size_t)M_ * C_ * 2;     // 16.8 MB
  u16* wqkvb = (u16*)p; p += (size_t)N1_ * C_ * 2;    //  6.3 MB
  u16* wob   = (u16*)p; p += (size_t)C_ * C_ * 2;     //  2.1 MB
  u16* qb    = (u16*)p; p += (size_t)M_ * C_ * 2;     // 16.8 MB  [B,H,T,64]
  u16* kb    = (u16*)p; p += (size_t)M_ * C_ * 2;     // 16.8 MB  [B,H,T,64]
  u16* vtb   = (u16*)p; p += (size_t)M_ * C_ * 2;     // 16.8 MB  tile-major swizzled
  u16* aob   = (u16*)p; p += (size_t)M_ * C_ * 2;     // 16.8 MB  [B,T,C]

  const int ncast = (M_ * C_ + N1_ * C_ + C_ * C_) / 4;
  cast_all<<<(ncast + 255) / 256, 256, 0, stream>>>(x, wqkv, wo, xb, wqkvb, wob);

  gemm_bt<0><<<dim3(N1_ / 128, M_ / 128), 256, 0, stream>>>(xb, wqkvb, qb, kb, vtb, C_, N1_);

  // grid (bh, qb): flat%8 == bh%8 -> all q-blocks of a head on one XCD
  flash_kernel<<<dim3(B_ * H_, T_ / 128), 256, 0, stream>>>(qb, kb, vtb, aob);

  gemm_bt<1><<<dim3(C_ / 128, M_ / 128), 256, 0, stream>>>(aob, wob, d_out, nullptr, nullptr, C_, C_);
}

// Round 13
// 251.403 us; speedup vs baseline: 1.0983x; 1.0134x over previous
//
#include <hip/hip_runtime.h>
#include <hip/hip_bf16.h>
#include <stdint.h>

// MHA fwd: x[4,2048,1024] fp32, w_qkv[3072,1024], w_o[1024,1024]
// bf16 MFMA pipeline: cast -> QKV gemm -> flash attention -> out gemm.
// R11: flash PV/rowsum on full-rate K=32 mfma via permuted QK key->row map.
// R12: flash LDS reads hoisted. R15: half-up packexp. flash=88.5us.
// R16: GEMM BK=64 + XOR swizzle (-14us). R17: dbuf null (-2). R18: LDS-bounce
// epilogue null (-0.5) -> epilogue/staging theories dead; GEMM cost is
// block-level: short K=1024 (16 iters) under-amortizes per-block fixed cost,
// and small tiles re-read operands (QKV A-traffic 403MB at 128x128).
// R19: both GEMMs -> BM=128 x BN=256, 512 thr (8 waves 2m x 4n, per-wave
// 64x64 = unchanged), BK=64, SINGLE-buffer 48KB LDS (dbuf was null; 48KB ->
// 3 blocks/CU = 24 waves/CU vs 8). QKV grid 12x64=768 = 3x256 exactly (no
// tail; the 256^2 8-phase alternative is 1 blk/CU + 384 wgs = 1.5 rounds =
// 75% tail, arithmetically null). 2x MFMA/block amortizes prologue/epilogue;
// A-traffic halved. Same verified swizzle + 2-barrier structure; simple
// scatter epilogues (R18 proved epilogue choice worth <1us).

#define B_   4
#define T_   2048
#define H_   16
#define DK_  64
#define C_   1024
#define M_   (B_*T_)    // 8192 rows
#define N1_  (3*C_)     // 3072
#define LOG2E 1.44269504088896340736f
#define SCFOLD (0.125f * LOG2E)   // folded into q at QKV epilogue

using short8  = __attribute__((ext_vector_type(8))) short;
using short4v = __attribute__((ext_vector_type(4))) short;
using f32x4   = __attribute__((ext_vector_type(4))) float;
typedef unsigned short u16;

__device__ __forceinline__ u16 f2bf(float f) {       // RNE (used in epilogues)
  unsigned u = __float_as_uint(f);
  u += 0x7FFF + ((u >> 16) & 1);
  return (u16)(u >> 16);
}

// exp2 + round-half-up-to-bf16 + pack 4 floats -> short4v: 4 exp + 4 add +
// 2 perm. u += 0x8000 before hi16 extraction = round-to-nearest (ties up):
// unbiased in practice, 1 VALU op/value. NaN-safe: exp2 outputs are positive
// normals; +0x8000 cannot carry into NaN/inf for values < 2^127.
__device__ __forceinline__ short4v packexp(f32x4 s) {
  unsigned u0 = __float_as_uint(__builtin_amdgcn_exp2f(s[0])) + 0x8000u;
  unsigned u1 = __float_as_uint(__builtin_amdgcn_exp2f(s[1])) + 0x8000u;
  unsigned u2 = __float_as_uint(__builtin_amdgcn_exp2f(s[2])) + 0x8000u;
  unsigned u3 = __float_as_uint(__builtin_amdgcn_exp2f(s[3])) + 0x8000u;
  union { unsigned w[2]; short4v s4; } cv;
  cv.w[0] = __builtin_amdgcn_perm(u1, u0, 0x07060302);  // {hi16(u1),hi16(u0)}
  cv.w[1] = __builtin_amdgcn_perm(u3, u2, 0x07060302);  // {hi16(u3),hi16(u2)}
  return cv.s4;
}

__device__ __forceinline__ short8 cat44(short4v a, short4v b) {
  return __builtin_shufflevector(a, b, 0, 1, 2, 3, 4, 5, 6, 7);
}

// async global->LDS, 16B per lane; lds ptr is wave-uniform base, HW adds lane*16
__device__ __forceinline__ void gld_lds16(void* lds, const void* g) {
  __builtin_amdgcn_global_load_lds(
      (__attribute__((address_space(1))) void*)(g),
      (__attribute__((address_space(3))) void*)(lds), 16, 0, 0);
}

// ---------------- fp32 -> bf16 cast (all three tensors, one launch) ----------
__global__ void cast_all(const float* __restrict__ x, const float* __restrict__ wq,
                         const float* __restrict__ wo, u16* __restrict__ xb,
                         u16* __restrict__ wqb, u16* __restrict__ wob) {
  const int nx = M_ * C_ / 4, nq = N1_ * C_ / 4;
  int i = blockIdx.x * blockDim.x + threadIdx.x;
  const float* src; u16* dst; int j;
  if (i < nx)            { src = x;  dst = xb;  j = i; }
  else if (i < nx + nq)  { src = wq; dst = wqb; j = i - nx; }
  else                   { src = wo; dst = wob; j = i - nx - nq; }
  float4 v = ((const float4*)src)[j];
  ushort4 o;
  o.x = f2bf(v.x); o.y = f2bf(v.y); o.z = f2bf(v.z); o.w = f2bf(v.w);
  ((ushort4*)dst)[j] = o;
}

// ---------------- BT GEMM: C[m,n] = sum_k A[m,k]*B[n,k] ----------------
// R19: 128x256 tile, BK=64, 512 thr = 8 waves in 2x4; each wave 64x64
// (4x4 MFMA 16x16x32, 2 K-substeps). Single-buffer 48KB LDS (3 blocks/CU).
// 2-barrier loop: barrier -> stage (async DMA) -> barrier(drains) -> compute.
// XOR source swizzle: store chunk cc=(s&7)^(row&7); read slot
// ((ks*4+quad)^(l15&7)) -> conflict-free (R16-verified pattern).
// T1 XCD block swizzle (nwg: 768 / 256, both %8==0).
// MODE 0: scatters qkv -> q (pre-scaled), k, V tile-major swizzled.
// MODE 1: fp32 C row-major [M,N].
template <int MODE>
__global__ __launch_bounds__(512)
void gemm_bt(const u16* __restrict__ A, const u16* __restrict__ Bm,
             void* __restrict__ out0, void* __restrict__ out1, void* __restrict__ out2,
             int K, int N) {
  __shared__ __attribute__((aligned(16))) u16 As[128 * 64];   // 16KB
  __shared__ __attribute__((aligned(16))) u16 Bs[256 * 64];   // 32KB
  const int tid  = threadIdx.x;
  const int w    = tid >> 6, lane = tid & 63;
  const int quad = lane >> 4, l15 = lane & 15;
  const int wm   = w >> 2, wn = w & 3;

  // XCD swizzle: remap so XCD i owns a contiguous n-fastest chunk of tiles.
  const int nxb = gridDim.x, nwg = nxb * gridDim.y;
  int flat = blockIdx.y * nxb + blockIdx.x;
  if ((nwg & 7) == 0) flat = (flat & 7) * (nwg >> 3) + (flat >> 3);
  const int m0 = (flat / nxb) * 128, n0 = (flat % nxb) * 256;

  f32x4 acc[4][4];
#pragma unroll
  for (int i = 0; i < 4; i++)
#pragma unroll
    for (int j = 0; j < 4; j++) acc[i][j] = f32x4{0.f, 0.f, 0.f, 0.f};

  const int xr = l15 & 7;          // read-side xor (== row&7 for frag rows)
  const int nkt = K >> 6;
  for (int kt = 0; kt < nkt; ++kt) {
    __syncthreads();               // prior-iter LDS reads done
    // stage A (128x64 = 1024 chunks, 2 issues) + B (256x64 = 2048, 4 issues)
#pragma unroll
    for (int c = 0; c < 2; ++c) {
      int s = c * 512 + tid;
      int row = s >> 3, cc = (s & 7) ^ (row & 7);
      gld_lds16(As + (c * 512 + w * 64) * 8, A  + (size_t)(m0 + row) * K + kt * 64 + cc * 8);
    }
#pragma unroll
    for (int c = 0; c < 4; ++c) {
      int s = c * 512 + tid;
      int row = s >> 3, cc = (s & 7) ^ (row & 7);
      gld_lds16(Bs + (c * 512 + w * 64) * 8, Bm + (size_t)(n0 + row) * K + kt * 64 + cc * 8);
    }
    __syncthreads();               // implicit vmcnt(0) drain: DMA landed
#pragma unroll
    for (int ks = 0; ks < 2; ++ks) {
      short8 af[4], bf[4];
#pragma unroll
      for (int i = 0; i < 4; i++)
        af[i] = *(const short8*)(As + (wm * 64 + i * 16 + l15) * 64 + (((ks << 2) | quad) ^ xr) * 8);
#pragma unroll
      for (int j = 0; j < 4; j++)
        bf[j] = *(const short8*)(Bs + (wn * 64 + j * 16 + l15) * 64 + (((ks << 2) | quad) ^ xr) * 8);
#pragma unroll
      for (int i = 0; i < 4; i++)
#pragma unroll
        for (int j = 0; j < 4; j++)
          acc[i][j] = __builtin_amdgcn_mfma_f32_16x16x32_bf16(af[i], bf[j], acc[i][j], 0, 0, 0);
    }
  }

  // epilogue: C/D layout col=lane&15, row=quad*4+reg  (m89-verified)
  if (MODE == 0) {
    u16* q  = (u16*)out0;
    u16* k  = (u16*)out1;
    u16* vt = (u16*)out2;
#pragma unroll
    for (int i = 0; i < 4; i++) {
      int m = m0 + wm * 64 + i * 16 + quad * 4;   // + r below; 128-row tile
      int b = m >> 11, t = m & 2047;              // t multiple of 4
#pragma unroll
      for (int j = 0; j < 4; j++) {
        int f = n0 + wn * 64 + j * 16 + l15;      // 256-col tile, one sblk
        int s = f >> 10, h = (f >> 6) & 15, d = f & 63;
        if (s == 2) {
          ushort4 pk;                              // keys t..t+3 of dim d
          pk.x = f2bf(acc[i][j][0]); pk.y = f2bf(acc[i][j][1]);
          pk.z = f2bf(acc[i][j][2]); pk.w = f2bf(acc[i][j][3]);
          int kt2  = t >> 6;
          int cw   = (t >> 3) & 7;                 // 8-key (16B) unit
          int pw   = cw ^ (d & 7);                 // bank-free b128 flash reads
          int half = (t >> 2) & 1;
          *(ushort4*)(vt + ((((size_t)(b * H_ + h) * 32 + kt2) * 64 + d) * 8 + pw) * 8 + half * 4) = pk;
        } else {
          u16* dst = (s == 0) ? q : k;
          float sc = (s == 0) ? SCFOLD : 1.0f;
#pragma unroll
          for (int r = 0; r < 4; r++)
            dst[(((size_t)(b * H_ + h)) * T_ + (t + r)) * DK_ + d] = f2bf(acc[i][j][r] * sc);
        }
      }
    }
  } else {
    float* outp = (float*)out0;
#pragma unroll
    for (int i = 0; i < 4; i++) {
      int m = m0 + wm * 64 + i * 16 + quad * 4;
#pragma unroll
      for (int j = 0; j < 4; j++) {
        int n = n0 + wn * 64 + j * 16 + l15;
#pragma unroll
        for (int r = 0; r < 4; r++)
          outp[(size_t)(m + r) * N + n] = acc[i][j][r];
      }
    }
  }
}

// ---------------- flash attention (K=32 PV, hoisted LDS reads) --------------
// grid (B*H, T/128), 256 thr. Wave w owns 32 Q-rows (2 x 16).
// S^T = K·Q^T via 16x16x32 with PERMUTED key->MFMA-row map: unit (u,h) loads
// K rows 32u + 8*(l15>>2) + 4h + (l15&3), so output reg r at lane (quad,l15)
// holds key 32u + 8*quad + 4h + r.  packexp(alpha)++packexp(beta) is then
// EXACTLY the K=32 A-fragment (k = quad*8 + j, keys 32u+8*quad..+7): PV and
// rowsum run as mfma_f32_16x16x32_bf16 (full-rate) with zero cross-lane ops.
// R12 schedule: all 8 K-frag reads + V(0) reads burst at tile top, then
// QK(0) -> QK(1) -> exp(0) -> read V(1) -> PV(0) -> exp(1) -> PV(1).
// Every ds_read is >=~150cy of issue distance from its consumer. No
// scheduling fences (R6: sched_barrier(0) costs ~12us of loop-carried
// overlap); single-barrier dbuf correctness rests on the compiler's
// vmcnt(0)+lgkmcnt(0) drain before s_barrier.
__global__ __launch_bounds__(256)
void flash_kernel(const u16* __restrict__ Q, const u16* __restrict__ Kg,
                  const u16* __restrict__ Vt, u16* __restrict__ AO) {
  __shared__ __attribute__((aligned(16))) u16 KVs[2][2][64 * 64];  // [buf][K/V]
  const int tid  = threadIdx.x;
  const int w    = tid >> 6, lane = tid & 63;
  const int quad = lane >> 4, l15 = lane & 15;
  const int bh   = blockIdx.x;
  const int q0   = blockIdx.y * 128;
  const u16* Qb = Q  + (size_t)bh * T_ * DK_;
  const u16* Kb = Kg + (size_t)bh * T_ * DK_;
  const u16* Vb = Vt + (size_t)bh * T_ * DK_;   // 32 tiles x 4096 u16, contiguous

  // Q fragments (B-operand of S^T = K·Q^T): lane n=q=l15 holds d=quad*8+j.
  short8 qf[2][2];
#pragma unroll
  for (int mi = 0; mi < 2; mi++)
#pragma unroll
    for (int ks = 0; ks < 2; ks++)
      qf[mi][ks] = *(const short8*)(Qb + (size_t)(q0 + w * 32 + mi * 16 + l15) * DK_ + ks * 32 + quad * 8);

  // ones A/B-fragment (bf16 1.0 x8) for K=32 rowsum MFMA
  short8 ones8;
#pragma unroll
  for (int z = 0; z < 8; z++) ones8[z] = (short)0x3F80;

  f32x4 O[2][4];       // rows q=quad*4+r, cols d=dj*16+l15 (C/D layout)
  f32x4 rowsum[2];
#pragma unroll
  for (int mi = 0; mi < 2; mi++) {
    rowsum[mi] = f32x4{0.f, 0.f, 0.f, 0.f};
#pragma unroll
    for (int dj = 0; dj < 4; dj++) O[mi][dj] = f32x4{0.f, 0.f, 0.f, 0.f};
  }

  const int swz = l15 & 7;
  const int NT  = T_ / 64;
  // kt-invariant LDS offsets (elements)
  const int koff0 = ((quad) ^ swz) * 8;            // d 0..31 K chunk
  const int koff1 = ((4 + quad) ^ swz) * 8;        // d 32..63 K chunk
  const int rA    = ((l15 >> 2) << 3) + (l15 & 3); // permuted key-row base
  const int voffu0 = ((quad) ^ swz) * 8;           // u=0 V chunk
  const int voffu1 = ((4 + quad) ^ swz) * 8;       // u=1 V chunk

  // stage tile kt into buffer b (async DMA). K: source-swizzled 16B chunks
  // with f(row) = (row&3)|(((row>>3)&1)<<2). V: linear copy (pre-swizzled).
  auto stage = [&](int kt, int b) {
#pragma unroll
    for (int c = 0; c < 2; ++c) {
      int s = c * 256 + tid;
      int row = s >> 3;
      int cc  = (s & 7) ^ ((row & 3) | (((row >> 3) & 1) << 2));
      gld_lds16(&KVs[b][0][(c * 256 + w * 64) * 8], Kb + (size_t)kt * 4096 + row * 64 + cc * 8);
      gld_lds16(&KVs[b][1][(c * 256 + w * 64) * 8], Vb + (size_t)kt * 4096 + s * 8);
    }
  };

  stage(0, 0);   // prologue

  for (int kt = 0; kt < NT; ++kt) {
    __syncthreads();               // DMA for buf[kt&1] landed during last iter
    if (kt + 1 < NT) stage(kt + 1, (kt + 1) & 1);   // hidden by compute below
    const u16* Ks = KVs[kt & 1][0];
    const u16* Vs = KVs[kt & 1][1];

    // ---- read burst: all K fragments (both units) + V fragments for u=0 ----
    const u16* krA0 = Ks + (rA)          * 64;   // u=0 h=0: keys 8*quad + r
    const u16* krB0 = Ks + (rA + 4)      * 64;   // u=0 h=1: keys 8*quad+4+r
    const u16* krA1 = Ks + (32 + rA)     * 64;   // u=1 h=0
    const u16* krB1 = Ks + (32 + rA + 4) * 64;   // u=1 h=1
    short8 ka0_0 = *(const short8*)(krA0 + koff0);
    short8 ka1_0 = *(const short8*)(krA0 + koff1);
    short8 kb0_0 = *(const short8*)(krB0 + koff0);
    short8 kb1_0 = *(const short8*)(krB0 + koff1);
    short8 ka0_1 = *(const short8*)(krA1 + koff0);
    short8 ka1_1 = *(const short8*)(krA1 + koff1);
    short8 kb0_1 = *(const short8*)(krB1 + koff0);
    short8 kb1_1 = *(const short8*)(krB1 + koff1);
    short8 vf0[4];
#pragma unroll
    for (int dj = 0; dj < 4; dj++)
      vf0[dj] = *(const short8*)(Vs + (dj * 16 + l15) * 64 + voffu0);

    // ---- QK(0): 8 MFMA ----
    f32x4 sA0c = f32x4{0.f, 0.f, 0.f, 0.f}, sA1c = sA0c, sB0c = sA0c, sB1c = sA0c;
    sA0c = __builtin_amdgcn_mfma_f32_16x16x32_bf16(ka0_0, qf[0][0], sA0c, 0, 0, 0);
    sA0c = __builtin_amdgcn_mfma_f32_16x16x32_bf16(ka1_0, qf[0][1], sA0c, 0, 0, 0);
    sA1c = __builtin_amdgcn_mfma_f32_16x16x32_bf16(ka0_0, qf[1][0], sA1c, 0, 0, 0);
    sA1c = __builtin_amdgcn_mfma_f32_16x16x32_bf16(ka1_0, qf[1][1], sA1c, 0, 0, 0);
    sB0c = __builtin_amdgcn_mfma_f32_16x16x32_bf16(kb0_0, qf[0][0], sB0c, 0, 0, 0);
    sB0c = __builtin_amdgcn_mfma_f32_16x16x32_bf16(kb1_0, qf[0][1], sB0c, 0, 0, 0);
    sB1c = __builtin_amdgcn_mfma_f32_16x16x32_bf16(kb0_0, qf[1][0], sB1c, 0, 0, 0);
    sB1c = __builtin_amdgcn_mfma_f32_16x16x32_bf16(kb1_0, qf[1][1], sB1c, 0, 0, 0);

    // ---- QK(1): 8 MFMA (K-frags read ~12 reads + 8 MFMAs ago) ----
    f32x4 sA0n = f32x4{0.f, 0.f, 0.f, 0.f}, sA1n = sA0n, sB0n = sA0n, sB1n = sA0n;
    sA0n = __builtin_amdgcn_mfma_f32_16x16x32_bf16(ka0_1, qf[0][0], sA0n, 0, 0, 0);
    sA0n = __builtin_amdgcn_mfma_f32_16x16x32_bf16(ka1_1, qf[0][1], sA0n, 0, 0, 0);
    sA1n = __builtin_amdgcn_mfma_f32_16x16x32_bf16(ka0_1, qf[1][0], sA1n, 0, 0, 0);
    sA1n = __builtin_amdgcn_mfma_f32_16x16x32_bf16(ka1_1, qf[1][1], sA1n, 0, 0, 0);
    sB0n = __builtin_amdgcn_mfma_f32_16x16x32_bf16(kb0_1, qf[0][0], sB0n, 0, 0, 0);
    sB0n = __builtin_amdgcn_mfma_f32_16x16x32_bf16(kb1_1, qf[0][1], sB0n, 0, 0, 0);
    sB1n = __builtin_amdgcn_mfma_f32_16x16x32_bf16(kb0_1, qf[1][0], sB1n, 0, 0, 0);
    sB1n = __builtin_amdgcn_mfma_f32_16x16x32_bf16(kb1_1, qf[1][1], sB1n, 0, 0, 0);

    // ---- exp/pack(0) (QK(0) results are 16 MFMAs old) ----
    short8 pa0 = cat44(packexp(sA0c), packexp(sB0c));
    short8 pa1 = cat44(packexp(sA1c), packexp(sB1c));

    // ---- read V fragments for u=1 (consumed after PV(0)+exp(1)) ----
    short8 vf1[4];
#pragma unroll
    for (int dj = 0; dj < 4; dj++)
      vf1[dj] = *(const short8*)(Vs + (dj * 16 + l15) * 64 + voffu1);

    // ---- rowsum(0) + PV(0): 10 MFMA (vf0 read at tile top) ----
    rowsum[0] = __builtin_amdgcn_mfma_f32_16x16x32_bf16(pa0, ones8, rowsum[0], 0, 0, 0);
    rowsum[1] = __builtin_amdgcn_mfma_f32_16x16x32_bf16(pa1, ones8, rowsum[1], 0, 0, 0);
#pragma unroll
    for (int dj = 0; dj < 4; dj++) {
      O[0][dj] = __builtin_amdgcn_mfma_f32_16x16x32_bf16(pa0, vf0[dj], O[0][dj], 0, 0, 0);
      O[1][dj] = __builtin_amdgcn_mfma_f32_16x16x32_bf16(pa1, vf0[dj], O[1][dj], 0, 0, 0);
    }

    // ---- exp/pack(1) ----
    short8 pb0 = cat44(packexp(sA0n), packexp(sB0n));
    short8 pb1 = cat44(packexp(sA1n), packexp(sB1n));

    // ---- rowsum(1) + PV(1): 10 MFMA (vf1 covered by PV(0)+exp(1)) ----
    rowsum[0] = __builtin_amdgcn_mfma_f32_16x16x32_bf16(pb0, ones8, rowsum[0], 0, 0, 0);
    rowsum[1] = __builtin_amdgcn_mfma_f32_16x16x32_bf16(pb1, ones8, rowsum[1], 0, 0, 0);
#pragma unroll
    for (int dj = 0; dj < 4; dj++) {
      O[0][dj] = __builtin_amdgcn_mfma_f32_16x16x32_bf16(pb0, vf1[dj], O[0][dj], 0, 0, 0);
      O[1][dj] = __builtin_amdgcn_mfma_f32_16x16x32_bf16(pb1, vf1[dj], O[1][dj], 0, 0, 0);
    }
  }

  // epilogue: rowsum[mi][r] holds the full key-sum for q-row quad*4+r
  const int b = bh >> 4, h = bh & 15;
#pragma unroll
  for (int mi = 0; mi < 2; mi++) {
#pragma unroll
    for (int r = 0; r < 4; r++) {
      float inv = 1.0f / rowsum[mi][r];
      int t = q0 + w * 32 + mi * 16 + quad * 4 + r;
#pragma unroll
      for (int dj = 0; dj < 4; dj++)
        AO[((size_t)(b * T_ + t)) * C_ + h * DK_ + dj * 16 + l15] = f2bf(O[mi][dj][r] * inv);
    }
  }
}

extern "C" void kernel_launch(void* const* d_in, const int* in_sizes, int n_in,
                              void* d_out, int out_size, void* d_ws, size_t ws_size,
                              hipStream_t stream) {
  const float* x    = (const float*)d_in[0];
  const float* wqkv = (const float*)d_in[1];
  const float* wo   = (const float*)d_in[2];

  char* p = (char*)d_ws;
  u16* xb    = (u16*)p; p += (size_t)M_ * C_ * 2;     // 16.8 MB
  u16* wqkvb = (u16*)p; p += (size_t)N1_ * C_ * 2;    //  6.3 MB
  u16* wob   = (u16*)p; p += (size_t)C_ * C_ * 2;     //  2.1 MB
  u16* qb    = (u16*)p; p += (size_t)M_ * C_ * 2;     // 16.8 MB  [B,H,T,64]
  u16* kb    = (u16*)p; p += (size_t)M_ * C_ * 2;     // 16.8 MB  [B,H,T,64]
  u16* vtb   = (u16*)p; p += (size_t)M_ * C_ * 2;     // 16.8 MB  tile-major swizzled
  u16* aob   = (u16*)p; p += (size_t)M_ * C_ * 2;     // 16.8 MB  [B,T,C]

  const int ncast = (M_ * C_ + N1_ * C_ + C_ * C_) / 4;
  cast_all<<<(ncast + 255) / 256, 256, 0, stream>>>(x, wqkv, wo, xb, wqkvb, wob);

  // 128x256 tiles: QKV grid 12x64 = 768 wgs (3 blocks/CU x 256 CUs, no tail)
  gemm_bt<0><<<dim3(N1_ / 256, M_ / 128), 512, 0, stream>>>(xb, wqkvb, qb, kb, vtb, C_, N1_);

  // grid (bh, qb): flat%8 == bh%8 -> all q-blocks of a head on one XCD
  flash_kernel<<<dim3(B_ * H_, T_ / 128), 256, 0, stream>>>(qb, kb, vtb, aob);

  // out grid 4x64 = 256 wgs
  gemm_bt<1><<<dim3(C_ / 256, M_ / 128), 512, 0, stream>>>(aob, wob, d_out, nullptr, nullptr, C_, C_);
}